// Round 5
// baseline (1752.574 us; speedup 1.0000x reference)
//
#include <hip/hip_runtime.h>
#include <cstdint>

#define S_LEN 32768
#define NV 256
#define NH 512
#define NR 256
#define NBIAS 1280

typedef short bf16x8 __attribute__((ext_vector_type(8)));
typedef float f32x4 __attribute__((ext_vector_type(4)));
typedef unsigned short ushort_t;

// ---------------- bf16 helpers (bit-level, RTNE) ----------------
__device__ __forceinline__ float b2f(ushort_t u) {
  return __uint_as_float(((uint32_t)u) << 16);
}
__device__ __forceinline__ ushort_t f2b(float f) {
  uint32_t x = __float_as_uint(f);
  uint32_t r = (x + 0x7fffu + ((x >> 16) & 1u)) >> 16;
  return (ushort_t)r;
}

// ---------------- async global->LDS staging ----------------
// R19: timed total was flat (1394/1434/1378/1453) across 4 structurally
// different GEMM internals -> the cost is BETWEEN dispatches (12 serial
// grid-wide launches, fill/drain ramps, HBM round-trips of just-written
// samples), not inside them. The Gibbs chain is ROW-INDEPENDENT: fuse the
// whole chain into ONE kernel; each block owns a 64-row band and runs all
// 13 band-GEMMs locally. Band data is same-block same-CU write->read
// (L1/L2 coherent; __syncthreads' vmcnt(0) drains stores between steps).
#define GLOAD_LDS16(gsrc, ldst)                                        \
  __builtin_amdgcn_global_load_lds(                                    \
      (const __attribute__((address_space(1))) void*)(gsrc),           \
      (__attribute__((address_space(3))) void*)(ldst), 16, 0, 0)

// ---------------- host threefry2x32 (key-chain derivation) ----------------
#define TFR(x0,x1,r) { x0 += x1; x1 = ((x1 << (r)) | (x1 >> (32 - (r)))); x1 ^= x0; }
__host__ __forceinline__ void tf2x32(uint32_t k0, uint32_t k1,
                                     uint32_t x0, uint32_t x1,
                                     uint32_t* o0, uint32_t* o1) {
  uint32_t k2 = k0 ^ k1 ^ 0x1BD11BDAu;
  x0 += k0; x1 += k1;
  TFR(x0,x1,13) TFR(x0,x1,15) TFR(x0,x1,26) TFR(x0,x1,6)
  x0 += k1; x1 += k2 + 1u;
  TFR(x0,x1,17) TFR(x0,x1,29) TFR(x0,x1,16) TFR(x0,x1,24)
  x0 += k2; x1 += k0 + 2u;
  TFR(x0,x1,13) TFR(x0,x1,15) TFR(x0,x1,26) TFR(x0,x1,6)
  x0 += k0; x1 += k1 + 3u;
  TFR(x0,x1,17) TFR(x0,x1,29) TFR(x0,x1,16) TFR(x0,x1,24)
  x0 += k1; x1 += k2 + 4u;
  TFR(x0,x1,13) TFR(x0,x1,15) TFR(x0,x1,26) TFR(x0,x1,6)
  x0 += k2; x1 += k0 + 5u;
  *o0 = x0; *o1 = x1;
}

// ---------------- device RNG: murmur3 full-avalanche counter hash ----------------
__device__ __forceinline__ uint32_t fast_hash(uint32_t k0, uint32_t k1, uint32_t idx) {
  uint32_t h = idx ^ k0;
  h *= 0xCC9E2D51u; h = (h << 15) | (h >> 17); h *= 0x1B873593u;
  h ^= k1;
  h ^= h >> 16; h *= 0x85EBCA6Bu;
  h ^= h >> 13; h *= 0xC2B2AE35u;
  h ^= h >> 16;
  return h;
}

__device__ __forceinline__ float wave_reduce(float v) {
#pragma unroll
  for (int o = 32; o > 0; o >>= 1) v += __shfl_down(v, o, 64);
  return v;
}
__device__ __forceinline__ float softplusf(float z) {
  return fmaxf(z, 0.f) + log1pf(expf(-fabsf(z)));
}

// ---------------- epilogue flags ----------------
#define F_SAMP  4    // Bernoulli sample -> C (bf16 0/1)
#define F_H1    8    // sigmoid -> C2 (bf16)
#define F_FE    16   // softplus sum -> feR (feR -= sign*sum)
#define F_MON   32   // monitor sum vs vseqf -> monR
#define F_DOTB  64   // fe_sum += p * bias_elem
#define F_DOTS  128  // fe_sum += sample * bias_elem

struct ChainArgs {
  const ushort_t* vseq_bf;   // [S,256]
  const ushort_t* shifted;   // [S,256]
  const ushort_t* BTw1;      // [512,256] = W1^T
  const ushort_t* BTw1t;     // [256,512] = W1
  const ushort_t* BTw2;      // [512,512] = W2^T
  const ushort_t* BTw2t;     // [512,512] = W2
  const ushort_t* Wycat;     // [1280,256]
  const float* bveccat;      // [1280]
  const float* v_seq;        // [S,256] f32
  const ushort_t* bias_cat;  // [S,1280]
  ushort_t* sampA;           // [S,512]
  ushort_t* sampB;           // [S,256]
  ushort_t* sampC;           // [S,512]
  ushort_t* h1buf;           // [S,512] (doubles as sampD)
  double* acc;
  uint32_t ka[20], kb[20];
};

// ------------- band GEMM: 64-row band, N in chunks of 256, KT = K+256 -------
// 4 waves laid out 1x4 in N; per wave 64x64 output (4x4 16x16 frags).
// Same LDS XOR swizzle / staging / RNG stream as the R4 kernel -> z bitwise
// identical -> identical sample bits.
template<int FLAGS>
__device__ __forceinline__ void band_gemm(
    int band0,
    const ushort_t* __restrict__ A, const ushort_t* __restrict__ BT,
    int N, int K,
    const ushort_t* __restrict__ Ax, const ushort_t* __restrict__ BXT,
    const float* __restrict__ bvec,
    ushort_t* __restrict__ C, ushort_t* __restrict__ C2,
    const ushort_t* __restrict__ biasm, int boff,
    const float* __restrict__ vseqf,
    float sign, uint32_t rk0, uint32_t rk1,
    float& feR, float& monR,
    ushort_t* As0, ushort_t* As1, ushort_t* Bs0, ushort_t* Bs1) {
  const int tid = threadIdx.x;
  const int lane = tid & 63, wave = tid >> 6;
  const int q = lane >> 4, l16 = lane & 15;
  const int KT = K + 256;
  const ushort_t* Aband = A + (size_t)band0 * K;
  const ushort_t* Axband = Ax + (size_t)band0 * 256;

  for (int n0c = 0; n0c < N; n0c += 256) {
    f32x4 acc[4][4];
#pragma unroll
    for (int mt = 0; mt < 4; mt++)
#pragma unroll
      for (int nt = 0; nt < 4; nt++) acc[mt][nt] = (f32x4){0.f, 0.f, 0.f, 0.f};

    auto stage = [&](ushort_t* As, ushort_t* Bs, int kks) {
      const ushort_t* Ap; const ushort_t* Bp; int ld, k0;
      if (kks < K) { Ap = Aband; Bp = BT + (size_t)n0c * K; ld = K; k0 = kks; }
      else { Ap = Axband; Bp = BXT + (size_t)n0c * 256; ld = 256; k0 = kks - K; }
#pragma unroll
      for (int j = 0; j < 2; j++) {            // A tile: 64 rows x 64 cols
        int c = j * 256 + tid;
        int r = c >> 3, bl = c & 7, bg = bl ^ (r & 7);
        (void)bl;
        GLOAD_LDS16(&Ap[(size_t)r * ld + k0 + bg * 8], &As[(j * 256 + wave * 64) * 8]);
      }
#pragma unroll
      for (int j = 0; j < 8; j++) {            // B tile: 256 rows x 64 cols
        int c = j * 256 + tid;
        int r = c >> 3, bl = c & 7, bg = bl ^ (r & 7);
        (void)bl;
        GLOAD_LDS16(&Bp[(size_t)r * ld + k0 + bg * 8], &Bs[(j * 256 + wave * 64) * 8]);
      }
    };
    auto compute = [&](const ushort_t* As, const ushort_t* Bs) {
#pragma unroll
      for (int c = 0; c < 2; c++) {
        bf16x8 af[4], bf[4];
#pragma unroll
        for (int mt = 0; mt < 4; mt++) {
          int r = mt * 16 + l16;
          af[mt] = *(const bf16x8*)&As[r * 64 + (((c * 4 + q) ^ (r & 7)) * 8)];
        }
#pragma unroll
        for (int nt = 0; nt < 4; nt++) {
          int r = wave * 64 + nt * 16 + l16;
          bf[nt] = *(const bf16x8*)&Bs[r * 64 + (((c * 4 + q) ^ (r & 7)) * 8)];
        }
#pragma unroll
        for (int mt = 0; mt < 4; mt++)
#pragma unroll
          for (int nt = 0; nt < 4; nt++)
            acc[mt][nt] = __builtin_amdgcn_mfma_f32_16x16x32_bf16(
                af[mt], bf[nt], acc[mt][nt], 0, 0, 0);
      }
    };

    // 2-phase pipeline; KT/64 is even (512 or 768).
    stage(As0, Bs0, 0);
    __syncthreads();
    for (int kk = 0; kk < KT; kk += 128) {
      stage(As1, Bs1, kk + 64);
      compute(As0, Bs0);
      __syncthreads();
      if (kk + 128 < KT) stage(As0, Bs0, kk + 128);
      compute(As1, Bs1);
      __syncthreads();
    }

    float fe_sum = 0.f, mon_sum = 0.f;
#pragma unroll
    for (int mt = 0; mt < 4; mt++) {
#pragma unroll
      for (int nt = 0; nt < 4; nt++) {
        const int gn = n0c + wave * 64 + nt * 16 + l16;
        const int gmb = band0 + mt * 16 + q * 4;
        const float bvv = bvec[gn];
        uint32_t h0 = 0, h1 = 0;
        if constexpr (FLAGS & F_SAMP) {
          uint32_t pb = (uint32_t)((gmb >> 1) * N + gn);
          h0 = fast_hash(rk0, rk1, pb);                   // rows gmb, gmb+1
          h1 = fast_hash(rk0, rk1, pb + (uint32_t)N);     // rows gmb+2, gmb+3
        }
#pragma unroll
        for (int rg = 0; rg < 4; rg++) {
          const int gm = gmb + rg;
          const size_t idx = (size_t)gm * N + gn;
          float z = acc[mt][nt][rg] + bvv;  // matrix bias in acc via K-ext
          float be = 0.f;
          if constexpr (FLAGS & (F_DOTB | F_DOTS))
            be = b2f(biasm[(size_t)gm * NBIAS + boff + gn]);
          if constexpr (FLAGS & (F_SAMP | F_H1 | F_MON)) {
            float e = __expf(-z);
            if constexpr (FLAGS & F_SAMP) {
              uint32_t hb = (rg & 2) ? h1 : h0;
              uint32_t ub = (rg & 1) ? (hb >> 16) : (hb & 0xffffu);
              float uu = (float)ub * (1.0f / 65536.0f);
              bool sbit = fmaf(uu, e, uu) < 1.f;  // u < sigmoid(z)
              C[idx] = sbit ? (ushort_t)0x3f80 : (ushort_t)0;
              if constexpr (FLAGS & F_DOTS) fe_sum += sbit ? be : 0.f;
            }
            if constexpr (FLAGS & (F_H1 | F_MON)) {
              float pp = __builtin_amdgcn_rcpf(1.f + e);
              if constexpr (FLAGS & F_H1) C2[idx] = f2b(pp);
              if constexpr (FLAGS & F_DOTB) fe_sum += pp * be;
              if constexpr (FLAGS & F_MON) {
                float v = vseqf[idx];
                mon_sum += (v != 0.f) ? logf(pp + 1e-10f) : logf(1.f - pp + 1e-10f);
              }
            }
          }
          if constexpr (FLAGS & F_FE) fe_sum += softplusf(z);
        }
      }
    }
    feR -= sign * fe_sum;
    monR += mon_sum;
    // Drain epilogue stores (implicit vmcnt(0)) + LDS safety before the next
    // chunk/step stages from matrices this step just wrote.
    __syncthreads();
  }
}

// ---------------- the fused Gibbs-chain kernel ----------------
__global__ __launch_bounds__(256, 2)
void fused_chain(ChainArgs a) {
  __shared__ ushort_t As0[64 * 64], As1[64 * 64];
  __shared__ ushort_t Bs0[256 * 64], Bs1[256 * 64];
  const int band0 = (int)blockIdx.x * 64;
  float feR = 0.f, monR = 0.f;
  ushort_t* sampD = a.h1buf;  // alias: h1buf read (A2_0) before sampD written (B2_0)
  const ushort_t* Wy_v  = a.Wycat;
  const ushort_t* Wy_h1 = a.Wycat + 256 * 256;
  const ushort_t* Wy_h2 = a.Wycat + 768 * 256;
  const float* bv_v  = a.bveccat;
  const float* bv_h1 = a.bveccat + 256;
  const float* bv_h2 = a.bveccat + 768;

  // G1: h1 probs + sample, cost1 -= softplus, cost2 -= h1.bh1t
  band_gemm<F_SAMP | F_H1 | F_FE | F_DOTB>(band0, a.vseq_bf, a.BTw1, 512, 256,
      a.shifted, Wy_h1, bv_h1, a.sampA, a.h1buf, a.bias_cat, 256, nullptr,
      1.0f, a.ka[0], a.kb[0], feR, monR, As0, As1, Bs0, Bs1);

  // RBM1 chain
#pragma unroll 1
  for (int it = 0; it < 4; it++) {
    band_gemm<F_SAMP>(band0, a.sampA, a.BTw1t, 256, 512, a.shifted, Wy_v, bv_v,
        a.sampB, nullptr, a.bias_cat, 0, nullptr, 0.f,
        a.ka[2 * it + 1], a.kb[2 * it + 1], feR, monR, As0, As1, Bs0, Bs1);
    band_gemm<F_SAMP>(band0, a.sampB, a.BTw1, 512, 256, a.shifted, Wy_h1, bv_h1,
        a.sampA, nullptr, a.bias_cat, 256, nullptr, 0.f,
        a.ka[2 * it + 2], a.kb[2 * it + 2], feR, monR, As0, As1, Bs0, Bs1);
  }
  // V4: final v sample + monitor + dot(sample, bv_t)
  band_gemm<F_SAMP | F_MON | F_DOTS>(band0, a.sampA, a.BTw1t, 256, 512,
      a.shifted, Wy_v, bv_v, a.sampB, nullptr, a.bias_cat, 0, a.v_seq,
      -1.0f, a.ka[9], a.kb[9], feR, monR, As0, As1, Bs0, Bs1);
  // FE1: +softplus(v_samp@W1 + bh1t)
  band_gemm<F_FE>(band0, a.sampB, a.BTw1, 512, 256, a.shifted, Wy_h1, bv_h1,
      nullptr, nullptr, a.bias_cat, 256, nullptr, -1.0f, 0u, 0u,
      feR, monR, As0, As1, Bs0, Bs1);

  // RBM2 chain
  band_gemm<F_SAMP | F_FE>(band0, a.h1buf, a.BTw2, 512, 512, a.shifted, Wy_h2,
      bv_h2, a.sampC, nullptr, a.bias_cat, 768, nullptr, 1.0f,
      a.ka[10], a.kb[10], feR, monR, As0, As1, Bs0, Bs1);
  band_gemm<F_SAMP>(band0, a.sampC, a.BTw2t, 512, 512, a.shifted, Wy_h1, bv_h1,
      sampD, nullptr, a.bias_cat, 256, nullptr, 0.f,
      a.ka[11], a.kb[11], feR, monR, As0, As1, Bs0, Bs1);
#pragma unroll 1
  for (int it = 1; it < 4; it++) {
    band_gemm<F_SAMP>(band0, sampD, a.BTw2, 512, 512, a.shifted, Wy_h2, bv_h2,
        a.sampC, nullptr, a.bias_cat, 768, nullptr, 0.f,
        a.ka[10 + 2 * it], a.kb[10 + 2 * it], feR, monR, As0, As1, Bs0, Bs1);
    band_gemm<F_SAMP>(band0, a.sampC, a.BTw2t, 512, 512, a.shifted, Wy_h1, bv_h1,
        sampD, nullptr, a.bias_cat, 256, nullptr, 0.f,
        a.ka[11 + 2 * it], a.kb[11 + 2 * it], feR, monR, As0, As1, Bs0, Bs1);
  }
  band_gemm<F_SAMP>(band0, sampD, a.BTw2, 512, 512, a.shifted, Wy_h2, bv_h2,
      a.sampC, nullptr, a.bias_cat, 768, nullptr, 0.f,
      a.ka[18], a.kb[18], feR, monR, As0, As1, Bs0, Bs1);
  band_gemm<F_SAMP | F_DOTS>(band0, a.sampC, a.BTw2t, 512, 512, a.shifted,
      Wy_h1, bv_h1, sampD, nullptr, a.bias_cat, 256, nullptr, -1.0f,
      a.ka[19], a.kb[19], feR, monR, As0, As1, Bs0, Bs1);
  // FE2: +softplus(h1_samp@W2 + bh2t)
  band_gemm<F_FE>(band0, sampD, a.BTw2, 512, 512, a.shifted, Wy_h2, bv_h2,
      nullptr, nullptr, a.bias_cat, 768, nullptr, -1.0f, 0u, 0u,
      feR, monR, As0, As1, Bs0, Bs1);

  float s = wave_reduce(feR);
  if ((threadIdx.x & 63) == 0) atomicAdd(a.acc, (double)s);
  s = wave_reduce(monR);
  if ((threadIdx.x & 63) == 0) atomicAdd(a.acc + 1, (double)s);
}

// ---------------- plain GEMM + f32-vector bias (Arnn / bias_cat) ----------------
template<bool OUTF32, bool VDOT>
__global__ __launch_bounds__(256)
void gemm_bias(const ushort_t* __restrict__ A, const ushort_t* __restrict__ BT,
               const float* __restrict__ biasv, ushort_t* __restrict__ Cb,
               float* __restrict__ Cf, const float* __restrict__ vdata,
               double* __restrict__ dacc, int M, int N, int K) {
  __shared__ ushort_t As0[128 * 64], As1[128 * 64];
  __shared__ ushort_t Bs0[128 * 64], Bs1[128 * 64];
  const int tid = threadIdx.x;
  const int lane = tid & 63, wave = tid >> 6;
  const int wm = wave >> 1, wn = wave & 1;
  const int q = lane >> 4, l16 = lane & 15;
  const int m0 = blockIdx.y * 128, n0 = blockIdx.x * 128;

  f32x4 acc[4][4];
#pragma unroll
  for (int i = 0; i < 4; i++)
#pragma unroll
    for (int j = 0; j < 4; j++) acc[i][j] = (f32x4){0.f, 0.f, 0.f, 0.f};

  auto stage = [&](ushort_t* As, ushort_t* Bs, int kk) {
#pragma unroll
    for (int j = 0; j < 4; j++) {
      int c = j * 256 + tid;
      int r = c >> 3, bl = c & 7, bg = bl ^ (r & 7);
      (void)bl;
      const int ldso = (j * 256 + wave * 64) * 8;
      GLOAD_LDS16(&A[(size_t)(m0 + r) * K + kk + bg * 8], &As[ldso]);
      GLOAD_LDS16(&BT[(size_t)(n0 + r) * K + kk + bg * 8], &Bs[ldso]);
    }
  };
  auto compute = [&](const ushort_t* As, const ushort_t* Bs) {
#pragma unroll
    for (int c = 0; c < 2; c++) {
      bf16x8 af[4], bf[4];
#pragma unroll
      for (int mt = 0; mt < 4; mt++) {
        int r = wm * 64 + mt * 16 + l16;
        af[mt] = *(const bf16x8*)&As[r * 64 + (((c * 4 + q) ^ (r & 7)) * 8)];
      }
#pragma unroll
      for (int nt = 0; nt < 4; nt++) {
        int r = wn * 64 + nt * 16 + l16;
        bf[nt] = *(const bf16x8*)&Bs[r * 64 + (((c * 4 + q) ^ (r & 7)) * 8)];
      }
#pragma unroll
      for (int mt = 0; mt < 4; mt++)
#pragma unroll
        for (int nt = 0; nt < 4; nt++)
          acc[mt][nt] = __builtin_amdgcn_mfma_f32_16x16x32_bf16(
              af[mt], bf[nt], acc[mt][nt], 0, 0, 0);
    }
  };

  stage(As0, Bs0, 0);
  __syncthreads();
  for (int kk = 0; kk < K; kk += 128) {
    stage(As1, Bs1, kk + 64);
    compute(As0, Bs0);
    __syncthreads();
    if (kk + 128 < K) stage(As0, Bs0, kk + 128);
    compute(As1, Bs1);
    __syncthreads();
  }

  float dsum = 0.f;
#pragma unroll
  for (int mt = 0; mt < 4; mt++)
#pragma unroll
    for (int nt = 0; nt < 4; nt++) {
      const int gn = n0 + wn * 64 + nt * 16 + l16;
      const int gmb = m0 + wm * 64 + mt * 16 + q * 4;
      const float bvv = biasv[gn];
#pragma unroll
      for (int rg = 0; rg < 4; rg++) {
        const size_t idx = (size_t)(gmb + rg) * N + gn;
        float z = acc[mt][nt][rg] + bvv;
        if constexpr (OUTF32) Cf[idx] = z; else Cb[idx] = f2b(z);
        if constexpr (VDOT)
          if (n0 < 256) dsum += z * vdata[(size_t)(gmb + rg) * 256 + gn];
      }
    }
  if constexpr (VDOT) {
    if (n0 < 256) {
      float s = wave_reduce(dsum);
      if ((tid & 63) == 0) atomicAdd(dacc, (double)(-s));  // cost1 -= v.bv_t
    }
  }
}

// ---------------- chunked RNN scan v5 (R10-proven) ----------------
__global__ __launch_bounds__(1024, 1)
void rnn_scan(const float* __restrict__ Apre, const float* __restrict__ Wuu,
              ushort_t* __restrict__ shifted) {
  const int tid = threadIdx.x;
  const int j = tid >> 2;
  const int s = tid & 3;
  const int t_begin = blockIdx.x * 128;
  const int t_end = t_begin + 128;
  const int t0 = (t_begin >= 16) ? (t_begin - 16) : 0;

  float w[64];
#pragma unroll
  for (int i = 0; i < 64; i++) w[i] = Wuu[(size_t)(s * 64 + i) * 256 + j];

  __shared__ float u[2][280];
  __shared__ float asg[32 * 256];
  if (tid < 256) u[0][(tid >> 6) * 68 + (tid & 63)] = 0.f;
  if (blockIdx.x == 0 && s == 0) shifted[j] = 0;
  __syncthreads();

  const int jp = (j >> 6) * 68 + (j & 63);
  int p = 0;
  for (int tb = t0; tb < t_end; tb += 32) {
    int srow = tb + (tid >> 5);
    if (srow >= S_LEN) srow = S_LEN - 1;
    int scol = (tid & 31) * 8;
    float4 a0 = *(const float4*)&Apre[(size_t)srow * 256 + scol];
    float4 a1 = *(const float4*)&Apre[(size_t)srow * 256 + scol + 4];
    *(float4*)&asg[(tid >> 5) * 256 + scol] = a0;
    *(float4*)&asg[(tid >> 5) * 256 + scol + 4] = a1;
    __syncthreads();
#pragma unroll 1
    for (int i = 0; i < 32; i++) {
      const int t = tb + i;
      if (t >= t_end) break;
      float p0 = 0.f, p1 = 0.f, p2 = 0.f, p3 = 0.f;
#pragma unroll
      for (int qq = 0; qq < 64; qq += 4) {
        float4 uv = *(const float4*)&u[p][s * 68 + qq];
        p0 = fmaf(uv.x, w[qq + 0], p0);
        p1 = fmaf(uv.y, w[qq + 1], p1);
        p2 = fmaf(uv.z, w[qq + 2], p2);
        p3 = fmaf(uv.w, w[qq + 3], p3);
      }
      float ps = (p0 + p1) + (p2 + p3);
      ps += __shfl_xor(ps, 1, 64);
      ps += __shfl_xor(ps, 2, 64);
      float z = asg[i * 256 + j] + ps;
      float e = __expf(2.f * z);
      float unew = 1.f - 2.f * __builtin_amdgcn_rcpf(e + 1.f);
      if (s == 0) {
        u[1 - p][jp] = unew;
        if (t >= t_begin && (t + 1) < S_LEN)
          shifted[(size_t)(t + 1) * 256 + j] = f2b(unew);
      }
      __syncthreads();
      p ^= 1;
    }
  }
}

// ---------------- single prep kernel ----------------
__global__ __launch_bounds__(256)
void prep_all(const float* __restrict__ v_seq, ushort_t* __restrict__ vseq_bf,
              const float* __restrict__ Wyv, const float* __restrict__ Wyh1,
              const float* __restrict__ Wyh2, ushort_t* __restrict__ Wycat,
              const float* __restrict__ W1, ushort_t* __restrict__ BTw1t,
              ushort_t* __restrict__ BTw1,
              const float* __restrict__ W2, ushort_t* __restrict__ BTw2t,
              ushort_t* __restrict__ BTw2,
              const float* __restrict__ Wvu, ushort_t* __restrict__ BTwvu,
              const float* __restrict__ bv, const float* __restrict__ bh1,
              const float* __restrict__ bh2, float* __restrict__ bveccat) {
  int b = blockIdx.x;
  const int tid = threadIdx.x;
  if (b < 32768) { int i = b * 256 + tid; vseq_bf[i] = f2b(v_seq[i]); return; }
  b -= 32768;
  if (b < 256)  { int i = b * 256 + tid; Wycat[i] = f2b(Wyv[i]); return; }
  b -= 256;
  if (b < 512)  { int i = b * 256 + tid; Wycat[65536 + i] = f2b(Wyh1[i]); return; }
  b -= 512;
  if (b < 512)  { int i = b * 256 + tid; Wycat[196608 + i] = f2b(Wyh2[i]); return; }
  b -= 512;
  if (b < 512)  { int i = b * 256 + tid; BTw1t[i] = f2b(W1[i]); return; }
  b -= 512;
  if (b < 1024) { int i = b * 256 + tid; BTw2t[i] = f2b(W2[i]); return; }
  b -= 1024;
  if (b < 256)  { int i = b * 256 + tid; int r = i >> 8, c = i & 255;
                  BTwvu[c * 256 + r] = f2b(Wvu[i]); return; }
  b -= 256;
  if (b < 512)  { int i = b * 256 + tid; int r = i >> 9, c = i & 511;
                  BTw1[(size_t)c * 256 + r] = f2b(W1[i]); return; }
  b -= 512;
  if (b < 1024) { int i = b * 256 + tid; int r = i >> 9, c = i & 511;
                  BTw2[(size_t)c * 512 + r] = f2b(W2[i]); return; }
  b -= 1024;
  { int i = b * 256 + tid;
    if (i < 1280)
      bveccat[i] = (i < 256) ? bv[i] : (i < 768) ? bh1[i - 256] : bh2[i - 768]; }
}

__global__ void finalize_kernel(const double* __restrict__ acc, float* __restrict__ out) {
  out[0] = (float)(acc[0] / (double)S_LEN);
  out[1] = (float)(acc[1] / (double)S_LEN);
}

// ---------------- host orchestration ----------------
extern "C" void kernel_launch(void* const* d_in, const int* in_sizes, int n_in,
                              void* d_out, int out_size, void* d_ws, size_t ws_size,
                              hipStream_t stream) {
  (void)in_sizes; (void)n_in; (void)out_size; (void)ws_size;
  const float* v_seq = (const float*)d_in[0];
  const float* W1    = (const float*)d_in[1];
  const float* bv    = (const float*)d_in[2];
  const float* bh1   = (const float*)d_in[3];
  const float* W2    = (const float*)d_in[4];
  const float* bh2   = (const float*)d_in[5];
  const float* Wyv   = (const float*)d_in[6];
  const float* Wyh1  = (const float*)d_in[7];
  const float* Wyh2  = (const float*)d_in[8];
  const float* Wvu   = (const float*)d_in[9];
  const float* Wuu   = (const float*)d_in[10];
  const float* bu    = (const float*)d_in[11];
  float* out = (float*)d_out;

  const size_t SN = (size_t)S_LEN * NV;   // 8.4M
  const size_t SH = (size_t)S_LEN * NH;   // 16.8M
  char* base = (char*)d_ws;
  size_t cur = 0;
  auto take = [&](size_t bytes) { size_t o = cur; cur += (bytes + 255) & ~(size_t)255; return o; };
  double*   acc      = (double*)  (base + take(64));
  ushort_t* BTwvu    = (ushort_t*)(base + take(65536 * 2));
  ushort_t* Wycat    = (ushort_t*)(base + take((size_t)NBIAS * NR * 2));
  float*    bveccat  = (float*)   (base + take(NBIAS * 4));
  ushort_t* BTw1     = (ushort_t*)(base + take(131072 * 2));   // W1^T [512,256]
  ushort_t* BTw1t    = (ushort_t*)(base + take(131072 * 2));   // W1   [256,512]
  ushort_t* BTw2     = (ushort_t*)(base + take(262144 * 2));   // W2^T [512,512]
  ushort_t* BTw2t    = (ushort_t*)(base + take(262144 * 2));   // W2   [512,512]
  ushort_t* vseq_bf  = (ushort_t*)(base + take(SN * 2));
  ushort_t* shifted  = (ushort_t*)(base + take(SN * 2));
  ushort_t* bias_cat = (ushort_t*)(base + take((size_t)S_LEN * NBIAS * 2)); // [S,1280]
  ushort_t* h1buf    = (ushort_t*)(base + take(SH * 2));       // h1 probs / sampD
  ushort_t* sampA    = (ushort_t*)(base + take(SH * 2));       // RBM1 h samples
  ushort_t* sampB    = (ushort_t*)(base + take(SN * 2));       // RBM1 v samples
  ushort_t* sampC    = (ushort_t*)(base + take(SH * 2));       // RBM2 h2 samples
  float* Arnn = (float*)bias_cat;   // consumed by rnn before bias GEMM

  uint32_t ka[20], kb[20];
  uint32_t K0 = 0u, K1 = 42u;
  for (int it = 0; it < 10; it++) {
    uint32_t n0, n1, a0, a1, b0, b1;
    tf2x32(K0, K1, 0u, 0u, &n0, &n1);
    tf2x32(K0, K1, 0u, 1u, &a0, &a1);
    tf2x32(K0, K1, 0u, 2u, &b0, &b1);
    ka[2 * it] = a0; kb[2 * it] = a1;
    ka[2 * it + 1] = b0; kb[2 * it + 1] = b1;
    K0 = n0; K1 = n1;
  }

  hipMemsetAsync(acc, 0, 2 * sizeof(double), stream);

  dim3 blk(256);
  prep_all<<<dim3(37381), blk, 0, stream>>>(
      v_seq, vseq_bf, Wyv, Wyh1, Wyh2, Wycat, W1, BTw1t, BTw1,
      W2, BTw2t, BTw2, Wvu, BTwvu, bv, bh1, bh2, bveccat);

  const int M = S_LEN;
  gemm_bias<true, false><<<dim3(2, M / 128), blk, 0, stream>>>(
      vseq_bf, BTwvu, bu, nullptr, Arnn, nullptr, nullptr, M, NV, NV);
  rnn_scan<<<dim3(S_LEN / 128), dim3(1024), 0, stream>>>(Arnn, Wuu, shifted);
  gemm_bias<false, true><<<dim3(NBIAS / 128, M / 128), blk, 0, stream>>>(
      shifted, Wycat, bveccat, bias_cat, nullptr, v_seq, acc, M, NBIAS, NR);

  ChainArgs a;
  a.vseq_bf = vseq_bf; a.shifted = shifted;
  a.BTw1 = BTw1; a.BTw1t = BTw1t; a.BTw2 = BTw2; a.BTw2t = BTw2t;
  a.Wycat = Wycat; a.bveccat = bveccat; a.v_seq = v_seq; a.bias_cat = bias_cat;
  a.sampA = sampA; a.sampB = sampB; a.sampC = sampC; a.h1buf = h1buf;
  a.acc = acc;
  for (int i = 0; i < 20; i++) { a.ka[i] = ka[i]; a.kb[i] = kb[i]; }

  fused_chain<<<dim3(S_LEN / 64), blk, 0, stream>>>(a);

  finalize_kernel<<<1, 1, 0, stream>>>(acc, out);
}

// Round 6
// 1429.378 us; speedup vs baseline: 1.2261x; 1.2261x over previous
//
#include <hip/hip_runtime.h>
#include <cstdint>

#define S_LEN 32768
#define NV 256
#define NH 512
#define NR 256

typedef short bf16x8 __attribute__((ext_vector_type(8)));
typedef float f32x4 __attribute__((ext_vector_type(4)));
typedef unsigned short ushort_t;

// ---------------- bf16 helpers (bit-level, RTNE) ----------------
__device__ __forceinline__ float b2f(ushort_t u) {
  return __uint_as_float(((uint32_t)u) << 16);
}
__device__ __forceinline__ ushort_t f2b(float f) {
  uint32_t x = __float_as_uint(f);
  uint32_t r = (x + 0x7fffu + ((x >> 16) & 1u)) >> 16;
  return (ushort_t)r;
}

// ---------------- async global->LDS staging ----------------
// R20: every variant R1-R5 sat on the same line: time = L2-miss traffic /
// ~1.4 TB/s effective BW (R5 fused: 2.18 GB @ 1.50 TB/s = 1456us exactly).
// So cut BYTES, not compute structure:
//  (a) XCD-chunked bijective blockIdx swizzle -> x-sibling blocks (same A /
//      shifted panel) land on ONE XCD's L2 instead of 8 (panel fetched ~1x).
//  (b) bias_cat deleted entirely: K-ext accumulator SPLIT (main-K -> acc,
//      ext-K -> accB) reconstructs bias on the fly: be = accB + bvec,
//      z = acc + accB + bvec. Kills the 84MB bias_cat write + 84MB reads +
//      the producer GEMM dispatch (which re-fetched shifted ~10x). VDOT
//      folds into V[0] (its own K-ext IS bv_t).
#define GLOAD_LDS16(gsrc, ldst)                                        \
  __builtin_amdgcn_global_load_lds(                                    \
      (const __attribute__((address_space(1))) void*)(gsrc),           \
      (__attribute__((address_space(3))) void*)(ldst), 16, 0, 0)

// ---------------- host threefry2x32 (key-chain derivation) ----------------
#define TFR(x0,x1,r) { x0 += x1; x1 = ((x1 << (r)) | (x1 >> (32 - (r)))); x1 ^= x0; }
__host__ __forceinline__ void tf2x32(uint32_t k0, uint32_t k1,
                                     uint32_t x0, uint32_t x1,
                                     uint32_t* o0, uint32_t* o1) {
  uint32_t k2 = k0 ^ k1 ^ 0x1BD11BDAu;
  x0 += k0; x1 += k1;
  TFR(x0,x1,13) TFR(x0,x1,15) TFR(x0,x1,26) TFR(x0,x1,6)
  x0 += k1; x1 += k2 + 1u;
  TFR(x0,x1,17) TFR(x0,x1,29) TFR(x0,x1,16) TFR(x0,x1,24)
  x0 += k2; x1 += k0 + 2u;
  TFR(x0,x1,13) TFR(x0,x1,15) TFR(x0,x1,26) TFR(x0,x1,6)
  x0 += k0; x1 += k1 + 3u;
  TFR(x0,x1,17) TFR(x0,x1,29) TFR(x0,x1,16) TFR(x0,x1,24)
  x0 += k1; x1 += k2 + 4u;
  TFR(x0,x1,13) TFR(x0,x1,15) TFR(x0,x1,26) TFR(x0,x1,6)
  x0 += k2; x1 += k0 + 5u;
  *o0 = x0; *o1 = x1;
}

// ---------------- device RNG: murmur3 full-avalanche counter hash ----------------
__device__ __forceinline__ uint32_t fast_hash(uint32_t k0, uint32_t k1, uint32_t idx) {
  uint32_t h = idx ^ k0;
  h *= 0xCC9E2D51u; h = (h << 15) | (h >> 17); h *= 0x1B873593u;
  h ^= k1;
  h ^= h >> 16; h *= 0x85EBCA6Bu;
  h ^= h >> 13; h *= 0xC2B2AE35u;
  h ^= h >> 16;
  return h;
}

__device__ __forceinline__ float wave_reduce(float v) {
#pragma unroll
  for (int o = 32; o > 0; o >>= 1) v += __shfl_down(v, o, 64);
  return v;
}
__device__ __forceinline__ float softplusf(float z) {
  return fmaxf(z, 0.f) + log1pf(expf(-fabsf(z)));
}

// ---------------- epilogue flags ----------------
#define F_SAMP  4    // Bernoulli sample -> C (bf16 0/1)
#define F_H1    8    // sigmoid -> C2 (bf16)
#define F_FE    16   // softplus sum -> fe_acc (acc += -sign*sum)
#define F_MON   32   // monitor sum vs vseqf -> mon_acc
#define F_DOTB  64   // fe_sum += p * be       (h1 . bh1t, folded into G1)
#define F_DOTS  128  // fe_sum += sample * be  (sample-side dots)
#define F_DOTV  256  // fe_sum += v_seq * be   (v_seq . bv_t, folded into V0)

struct GemmArgs {
  const ushort_t* A;    // [M,K] bf16
  const ushort_t* BT;   // [N,K] bf16
  const ushort_t* Ax;   // shifted [M,256] bf16 (bias K-extension, A side)
  const ushort_t* BXT;  // Wycat slice [N,256] bf16 (bias K-ext, B side)
  const float* bvec;    // bveccat slice (f32 per-column bias)
  ushort_t* C;          // sample out [M,N] (bf16 0/1)
  ushort_t* C2;         // sigmoid out (F_H1, bf16)
  const float* vseqf;   // f32 v_seq (F_MON / F_DOTV)
  double* fe_acc;
  double* mon_acc;
  float sign;
  uint32_t rk0, rk1;
  int N, K, nbx;        // K = main K (ext adds 256); nbx = N/128
};

// XCD-chunked bijective swizzle. Hardware round-robins consecutive linear
// block ids across the 8 XCDs; remap so each XCD executes a CONTIGUOUS chunk
// of the (x-fastest) work space -> x-sibling blocks (same A/Ax panel) share
// one XCD's L2. gridDim.y==256 always -> nwg%8==0 -> bijective. gx is pow2.
__device__ __forceinline__ void xcd_swz(int* bx, int* by) {
  const int gx = (int)gridDim.x;
  const int lin = (int)blockIdx.y * gx + (int)blockIdx.x;
  const int cpx = (gx * (int)gridDim.y) >> 3;
  const int w = (lin & 7) * cpx + (lin >> 3);
  const int lg = 31 - __clz(gx);
  *by = w >> lg;
  *bx = w & (gx - 1);
}

// ---------------- core GEMM body — split-acc fused-bias-K + 2-phase staging ----
template<int FLAGS>
__device__ __forceinline__ void run_gemm(const GemmArgs& g, int bx, int by,
                                         ushort_t* __restrict__ As0,
                                         ushort_t* __restrict__ As1,
                                         ushort_t* __restrict__ Bs0,
                                         ushort_t* __restrict__ Bs1) {
  constexpr bool HASB = (FLAGS & (F_DOTB | F_DOTS | F_DOTV)) != 0;
  const int tid = threadIdx.x;
  const int lane = tid & 63, wave = tid >> 6;
  const int wm = wave >> 1, wn = wave & 1;
  const int q = lane >> 4, l16 = lane & 15;
  const int m0 = by * 128, n0 = bx * 128;
  const int N = g.N, K = g.K;
  const int KT = K + 256;            // +bias extension

  f32x4 acc[4][4];
  f32x4 accB[4][4];                  // ext-K accumulator (only live if HASB)
#pragma unroll
  for (int mt = 0; mt < 4; mt++)
#pragma unroll
    for (int nt = 0; nt < 4; nt++) {
      acc[mt][nt] = (f32x4){0.f, 0.f, 0.f, 0.f};
      if constexpr (HASB) accB[mt][nt] = (f32x4){0.f, 0.f, 0.f, 0.f};
    }

  auto stage = [&](ushort_t* As, ushort_t* Bs, int kks) {
    const ushort_t* Ap; const ushort_t* Bp; size_t lda; int k0;
    if (kks < K) { Ap = g.A;  Bp = g.BT;  lda = (size_t)K; k0 = kks; }
    else         { Ap = g.Ax; Bp = g.BXT; lda = 256;       k0 = kks - K; }
#pragma unroll
    for (int j = 0; j < 4; j++) {
      int c = j * 256 + tid;
      int r = c >> 3, bl = c & 7, bg = bl ^ (r & 7);
      (void)bl;
      const int ldso = (j * 256 + wave * 64) * 8;  // wave-uniform; lane adds *16B
      GLOAD_LDS16(&Ap[(size_t)(m0 + r) * lda + k0 + bg * 8], &As[ldso]);
      GLOAD_LDS16(&Bp[(size_t)(n0 + r) * lda + k0 + bg * 8], &Bs[ldso]);
    }
  };
  auto compute_into = [&](f32x4 (&ac)[4][4], const ushort_t* As, const ushort_t* Bs) {
#pragma unroll
    for (int c = 0; c < 2; c++) {
      bf16x8 af[4], bf[4];
#pragma unroll
      for (int mt = 0; mt < 4; mt++) {
        int r = wm * 64 + mt * 16 + l16;
        af[mt] = *(const bf16x8*)&As[r * 64 + (((c * 4 + q) ^ (r & 7)) * 8)];
      }
#pragma unroll
      for (int nt = 0; nt < 4; nt++) {
        int r = wn * 64 + nt * 16 + l16;
        bf[nt] = *(const bf16x8*)&Bs[r * 64 + (((c * 4 + q) ^ (r & 7)) * 8)];
      }
#pragma unroll
      for (int mt = 0; mt < 4; mt++)
#pragma unroll
        for (int nt = 0; nt < 4; nt++)
          ac[mt][nt] = __builtin_amdgcn_mfma_f32_16x16x32_bf16(
              af[mt], bf[nt], ac[mt][nt], 0, 0, 0);
    }
  };

  // 2-phase pipeline; KT/128 iterations (KT in {512,768}), K%128==0 so the
  // main/ext boundary never splits an iteration pair's chunk classification.
  stage(As0, Bs0, 0);
  __syncthreads();
  for (int kk = 0; kk < KT; kk += 128) {
    stage(As1, Bs1, kk + 64);
    if (HASB && kk >= K) compute_into(accB, As0, Bs0);
    else                 compute_into(acc,  As0, Bs0);
    __syncthreads();
    if (kk + 128 < KT) stage(As0, Bs0, kk + 128);
    if (HASB && (kk + 64) >= K) compute_into(accB, As1, Bs1);
    else                        compute_into(acc,  As1, Bs1);
    __syncthreads();
  }

  float fe_sum = 0.f, mon_sum = 0.f;
#pragma unroll
  for (int mt = 0; mt < 4; mt++) {
#pragma unroll
    for (int nt = 0; nt < 4; nt++) {
      const int gn = n0 + wn * 64 + nt * 16 + l16;
      const int gmb = m0 + wm * 64 + mt * 16 + q * 4;
      const float bvv = g.bvec[gn];
      uint32_t h0 = 0, h1 = 0;
      if constexpr (FLAGS & F_SAMP) {
        uint32_t pb = (uint32_t)((gmb >> 1) * N + gn);
        h0 = fast_hash(g.rk0, g.rk1, pb);               // rows gmb, gmb+1
        h1 = fast_hash(g.rk0, g.rk1, pb + (uint32_t)N); // rows gmb+2, gmb+3
      }
#pragma unroll
      for (int rg = 0; rg < 4; rg++) {
        const int gm = gmb + rg;
        const size_t idx = (size_t)gm * N + gn;
        float z, be = 0.f;
        if constexpr (HASB) {
          be = accB[mt][nt][rg] + bvv;   // on-the-fly bias (replaces bias_cat)
          z = acc[mt][nt][rg] + be;
        } else {
          z = acc[mt][nt][rg] + bvv;     // ext already merged into acc
        }
        if constexpr (FLAGS & F_DOTV) fe_sum += be * g.vseqf[idx];
        if constexpr (FLAGS & (F_SAMP | F_H1 | F_MON)) {
          float e = __expf(-z);
          if constexpr (FLAGS & F_SAMP) {
            uint32_t hb = (rg & 2) ? h1 : h0;
            uint32_t ub = (rg & 1) ? (hb >> 16) : (hb & 0xffffu);
            float uu = (float)ub * (1.0f / 65536.0f);
            bool sbit = fmaf(uu, e, uu) < 1.f;  // u < sigmoid(z)
            g.C[idx] = sbit ? (ushort_t)0x3f80 : (ushort_t)0;
            if constexpr (FLAGS & F_DOTS) fe_sum += sbit ? be : 0.f;
          }
          if constexpr (FLAGS & (F_H1 | F_MON)) {
            float pp = __builtin_amdgcn_rcpf(1.f + e);
            if constexpr (FLAGS & F_H1) g.C2[idx] = f2b(pp);
            if constexpr (FLAGS & F_DOTB) fe_sum += pp * be;
            if constexpr (FLAGS & F_MON) {
              float v = g.vseqf[idx];
              mon_sum += (v != 0.f) ? logf(pp + 1e-10f) : logf(1.f - pp + 1e-10f);
            }
          }
        }
        if constexpr (FLAGS & F_FE) fe_sum += softplusf(z);
      }
    }
  }
  if constexpr (FLAGS & (F_FE | F_DOTB | F_DOTS | F_DOTV)) {
    float s = wave_reduce(fe_sum);
    if (lane == 0) atomicAdd(g.fe_acc, (double)(-g.sign * s));
  }
  if constexpr (FLAGS & F_MON) {
    float s = wave_reduce(mon_sum);
    if (lane == 0) atomicAdd(g.mon_acc, (double)s);
  }
}

template<int FLAGS>
__global__ __launch_bounds__(256)
void gemm_samp(GemmArgs g) {
  __shared__ ushort_t As0[128 * 64], As1[128 * 64];
  __shared__ ushort_t Bs0[128 * 64], Bs1[128 * 64];
  int bx, by;
  xcd_swz(&bx, &by);
  if (bx >= g.nbx) return;
  run_gemm<FLAGS>(g, bx, by, As0, As1, Bs0, Bs1);
}

// Paired launch: z=0 runs g0 (RBM1 step), z=1 runs g1 (RBM2 step) — independent.
template<int F0, int F1>
__global__ __launch_bounds__(256)
void gemm_pair(GemmArgs g0, GemmArgs g1) {
  __shared__ ushort_t As0[128 * 64], As1[128 * 64];
  __shared__ ushort_t Bs0[128 * 64], Bs1[128 * 64];
  int bx, by;
  xcd_swz(&bx, &by);
  if (blockIdx.z == 0) {
    if (bx >= g0.nbx) return;
    run_gemm<F0>(g0, bx, by, As0, As1, Bs0, Bs1);
  } else {
    if (bx >= g1.nbx) return;
    run_gemm<F1>(g1, bx, by, As0, As1, Bs0, Bs1);
  }
}

// ---------------- plain GEMM + f32-vector bias (Arnn pre-activation) ------------
__global__ __launch_bounds__(256)
void gemm_bias(const ushort_t* __restrict__ A, const ushort_t* __restrict__ BT,
               const float* __restrict__ biasv, float* __restrict__ Cf,
               int M, int N, int K) {
  __shared__ ushort_t As0[128 * 64], As1[128 * 64];
  __shared__ ushort_t Bs0[128 * 64], Bs1[128 * 64];
  const int tid = threadIdx.x;
  const int lane = tid & 63, wave = tid >> 6;
  const int wm = wave >> 1, wn = wave & 1;
  const int q = lane >> 4, l16 = lane & 15;
  int bx, by;
  xcd_swz(&bx, &by);
  const int m0 = by * 128, n0 = bx * 128;
  (void)lane;

  f32x4 acc[4][4];
#pragma unroll
  for (int i = 0; i < 4; i++)
#pragma unroll
    for (int j = 0; j < 4; j++) acc[i][j] = (f32x4){0.f, 0.f, 0.f, 0.f};

  auto stage = [&](ushort_t* As, ushort_t* Bs, int kk) {
#pragma unroll
    for (int j = 0; j < 4; j++) {
      int c = j * 256 + tid;
      int r = c >> 3, bl = c & 7, bg = bl ^ (r & 7);
      (void)bl;
      const int ldso = (j * 256 + wave * 64) * 8;
      GLOAD_LDS16(&A[(size_t)(m0 + r) * K + kk + bg * 8], &As[ldso]);
      GLOAD_LDS16(&BT[(size_t)(n0 + r) * K + kk + bg * 8], &Bs[ldso]);
    }
  };
  auto compute = [&](const ushort_t* As, const ushort_t* Bs) {
#pragma unroll
    for (int c = 0; c < 2; c++) {
      bf16x8 af[4], bf[4];
#pragma unroll
      for (int mt = 0; mt < 4; mt++) {
        int r = wm * 64 + mt * 16 + l16;
        af[mt] = *(const bf16x8*)&As[r * 64 + (((c * 4 + q) ^ (r & 7)) * 8)];
      }
#pragma unroll
      for (int nt = 0; nt < 4; nt++) {
        int r = wn * 64 + nt * 16 + l16;
        bf[nt] = *(const bf16x8*)&Bs[r * 64 + (((c * 4 + q) ^ (r & 7)) * 8)];
      }
#pragma unroll
      for (int mt = 0; mt < 4; mt++)
#pragma unroll
        for (int nt = 0; nt < 4; nt++)
          acc[mt][nt] = __builtin_amdgcn_mfma_f32_16x16x32_bf16(
              af[mt], bf[nt], acc[mt][nt], 0, 0, 0);
    }
  };

  stage(As0, Bs0, 0);
  __syncthreads();
  for (int kk = 0; kk < K; kk += 128) {
    stage(As1, Bs1, kk + 64);
    compute(As0, Bs0);
    __syncthreads();
    if (kk + 128 < K) stage(As0, Bs0, kk + 128);
    compute(As1, Bs1);
    __syncthreads();
  }

#pragma unroll
  for (int mt = 0; mt < 4; mt++)
#pragma unroll
    for (int nt = 0; nt < 4; nt++) {
      const int gn = n0 + wn * 64 + nt * 16 + l16;
      const int gmb = m0 + wm * 64 + mt * 16 + q * 4;
      const float bvv = biasv[gn];
#pragma unroll
      for (int rg = 0; rg < 4; rg++)
        Cf[(size_t)(gmb + rg) * N + gn] = acc[mt][nt][rg] + bvv;
    }
}

// ---------------- chunked RNN scan v5 (R10-proven) ----------------
__global__ __launch_bounds__(1024, 1)
void rnn_scan(const float* __restrict__ Apre, const float* __restrict__ Wuu,
              ushort_t* __restrict__ shifted) {
  const int tid = threadIdx.x;
  const int j = tid >> 2;
  const int s = tid & 3;
  const int t_begin = blockIdx.x * 128;
  const int t_end = t_begin + 128;
  const int t0 = (t_begin >= 16) ? (t_begin - 16) : 0;

  float w[64];
#pragma unroll
  for (int i = 0; i < 64; i++) w[i] = Wuu[(size_t)(s * 64 + i) * 256 + j];

  __shared__ float u[2][280];
  __shared__ float asg[32 * 256];
  if (tid < 256) u[0][(tid >> 6) * 68 + (tid & 63)] = 0.f;
  if (blockIdx.x == 0 && s == 0) shifted[j] = 0;
  __syncthreads();

  const int jp = (j >> 6) * 68 + (j & 63);
  int p = 0;
  for (int tb = t0; tb < t_end; tb += 32) {
    int srow = tb + (tid >> 5);
    if (srow >= S_LEN) srow = S_LEN - 1;
    int scol = (tid & 31) * 8;
    float4 a0 = *(const float4*)&Apre[(size_t)srow * 256 + scol];
    float4 a1 = *(const float4*)&Apre[(size_t)srow * 256 + scol + 4];
    *(float4*)&asg[(tid >> 5) * 256 + scol] = a0;
    *(float4*)&asg[(tid >> 5) * 256 + scol + 4] = a1;
    __syncthreads();
#pragma unroll 1
    for (int i = 0; i < 32; i++) {
      const int t = tb + i;
      if (t >= t_end) break;
      float p0 = 0.f, p1 = 0.f, p2 = 0.f, p3 = 0.f;
#pragma unroll
      for (int qq = 0; qq < 64; qq += 4) {
        float4 uv = *(const float4*)&u[p][s * 68 + qq];
        p0 = fmaf(uv.x, w[qq + 0], p0);
        p1 = fmaf(uv.y, w[qq + 1], p1);
        p2 = fmaf(uv.z, w[qq + 2], p2);
        p3 = fmaf(uv.w, w[qq + 3], p3);
      }
      float ps = (p0 + p1) + (p2 + p3);
      ps += __shfl_xor(ps, 1, 64);
      ps += __shfl_xor(ps, 2, 64);
      float z = asg[i * 256 + j] + ps;
      float e = __expf(2.f * z);
      float unew = 1.f - 2.f * __builtin_amdgcn_rcpf(e + 1.f);
      if (s == 0) {
        u[1 - p][jp] = unew;
        if (t >= t_begin && (t + 1) < S_LEN)
          shifted[(size_t)(t + 1) * 256 + j] = f2b(unew);
      }
      __syncthreads();
      p ^= 1;
    }
  }
}

// ---------------- single prep kernel ----------------
__global__ __launch_bounds__(256)
void prep_all(const float* __restrict__ v_seq, ushort_t* __restrict__ vseq_bf,
              const float* __restrict__ Wyv, const float* __restrict__ Wyh1,
              const float* __restrict__ Wyh2, ushort_t* __restrict__ Wycat,
              const float* __restrict__ W1, ushort_t* __restrict__ BTw1t,
              ushort_t* __restrict__ BTw1,
              const float* __restrict__ W2, ushort_t* __restrict__ BTw2t,
              ushort_t* __restrict__ BTw2,
              const float* __restrict__ Wvu, ushort_t* __restrict__ BTwvu,
              const float* __restrict__ bv, const float* __restrict__ bh1,
              const float* __restrict__ bh2, float* __restrict__ bveccat) {
  int b = blockIdx.x;
  const int tid = threadIdx.x;
  if (b < 32768) { int i = b * 256 + tid; vseq_bf[i] = f2b(v_seq[i]); return; }
  b -= 32768;
  if (b < 256)  { int i = b * 256 + tid; Wycat[i] = f2b(Wyv[i]); return; }
  b -= 256;
  if (b < 512)  { int i = b * 256 + tid; Wycat[65536 + i] = f2b(Wyh1[i]); return; }
  b -= 512;
  if (b < 512)  { int i = b * 256 + tid; Wycat[196608 + i] = f2b(Wyh2[i]); return; }
  b -= 512;
  if (b < 512)  { int i = b * 256 + tid; BTw1t[i] = f2b(W1[i]); return; }
  b -= 512;
  if (b < 1024) { int i = b * 256 + tid; BTw2t[i] = f2b(W2[i]); return; }
  b -= 1024;
  if (b < 256)  { int i = b * 256 + tid; int r = i >> 8, c = i & 255;
                  BTwvu[c * 256 + r] = f2b(Wvu[i]); return; }
  b -= 256;
  if (b < 512)  { int i = b * 256 + tid; int r = i >> 9, c = i & 511;
                  BTw1[(size_t)c * 256 + r] = f2b(W1[i]); return; }
  b -= 512;
  if (b < 1024) { int i = b * 256 + tid; int r = i >> 9, c = i & 511;
                  BTw2[(size_t)c * 512 + r] = f2b(W2[i]); return; }
  b -= 1024;
  { int i = b * 256 + tid;
    if (i < 1280)
      bveccat[i] = (i < 256) ? bv[i] : (i < 768) ? bh1[i - 256] : bh2[i - 768]; }
}

__global__ void finalize_kernel(const double* __restrict__ acc, float* __restrict__ out) {
  out[0] = (float)(acc[0] / (double)S_LEN);
  out[1] = (float)(acc[1] / (double)S_LEN);
}

// ---------------- host orchestration ----------------
extern "C" void kernel_launch(void* const* d_in, const int* in_sizes, int n_in,
                              void* d_out, int out_size, void* d_ws, size_t ws_size,
                              hipStream_t stream) {
  (void)in_sizes; (void)n_in; (void)out_size; (void)ws_size;
  const float* v_seq = (const float*)d_in[0];
  const float* W1    = (const float*)d_in[1];
  const float* bv    = (const float*)d_in[2];
  const float* bh1   = (const float*)d_in[3];
  const float* W2    = (const float*)d_in[4];
  const float* bh2   = (const float*)d_in[5];
  const float* Wyv   = (const float*)d_in[6];
  const float* Wyh1  = (const float*)d_in[7];
  const float* Wyh2  = (const float*)d_in[8];
  const float* Wvu   = (const float*)d_in[9];
  const float* Wuu   = (const float*)d_in[10];
  const float* bu    = (const float*)d_in[11];
  float* out = (float*)d_out;

  const size_t SN = (size_t)S_LEN * NV;   // 8.4M
  const size_t SH = (size_t)S_LEN * NH;   // 16.8M
  char* base = (char*)d_ws;
  size_t cur = 0;
  auto take = [&](size_t bytes) { size_t o = cur; cur += (bytes + 255) & ~(size_t)255; return o; };
  double*   acc      = (double*)  (base + take(64));
  ushort_t* BTwvu    = (ushort_t*)(base + take(65536 * 2));
  ushort_t* Wycat    = (ushort_t*)(base + take((size_t)1280 * NR * 2));
  float*    bveccat  = (float*)   (base + take(1280 * 4));
  ushort_t* BTw1     = (ushort_t*)(base + take(131072 * 2));   // W1^T [512,256]
  ushort_t* BTw1t    = (ushort_t*)(base + take(131072 * 2));   // W1   [256,512]
  ushort_t* BTw2     = (ushort_t*)(base + take(262144 * 2));   // W2^T [512,512]
  ushort_t* BTw2t    = (ushort_t*)(base + take(262144 * 2));   // W2   [512,512]
  ushort_t* vseq_bf  = (ushort_t*)(base + take(SN * 2));
  ushort_t* shifted  = (ushort_t*)(base + take(SN * 2));
  float*    Arnn     = (float*)   (base + take(SN * 4));       // RNN pre-activation
  ushort_t* h1buf    = (ushort_t*)(base + take(SH * 2));       // h1 probs / sampD
  ushort_t* sampA    = (ushort_t*)(base + take(SH * 2));       // RBM1 h samples
  ushort_t* sampB    = (ushort_t*)(base + take(SN * 2));       // RBM1 v samples
  ushort_t* sampC    = (ushort_t*)(base + take(SH * 2));       // RBM2 h2 samples
  ushort_t* sampD = h1buf;   // alias: h1buf last read (A2g[0]) before sampD write

  uint32_t ka[20], kb[20];
  uint32_t K0 = 0u, K1 = 42u;
  for (int it = 0; it < 10; it++) {
    uint32_t n0, n1, a0, a1, b0, b1;
    tf2x32(K0, K1, 0u, 0u, &n0, &n1);
    tf2x32(K0, K1, 0u, 1u, &a0, &a1);
    tf2x32(K0, K1, 0u, 2u, &b0, &b1);
    ka[2 * it] = a0; kb[2 * it] = a1;
    ka[2 * it + 1] = b0; kb[2 * it + 1] = b1;
    K0 = n0; K1 = n1;
  }

  hipMemsetAsync(acc, 0, 2 * sizeof(double), stream);

  dim3 blk(256);
  prep_all<<<dim3(37381), blk, 0, stream>>>(
      v_seq, vseq_bf, Wyv, Wyh1, Wyh2, Wycat, W1, BTw1t, BTw1,
      W2, BTw2t, BTw2, Wvu, BTwvu, bv, bh1, bh2, bveccat);

  const int M = S_LEN;
  gemm_bias<<<dim3(2, M / 128), blk, 0, stream>>>(
      vseq_bf, BTwvu, bu, Arnn, M, NV, NV);
  rnn_scan<<<dim3(S_LEN / 128), dim3(1024), 0, stream>>>(Arnn, Wuu, shifted);

  const int OFF_BV = 0, OFF_BH1 = NV, OFF_BH2 = NV + NH;
  auto mk = [&](const ushort_t* A, const ushort_t* BT, int boff, ushort_t* C,
                ushort_t* C2, const float* vs, float sign, int key, int N, int K) {
    GemmArgs g;
    g.A = A; g.BT = BT;
    g.Ax = shifted;
    g.BXT = Wycat + (size_t)boff * 256;
    g.bvec = bveccat + boff;
    g.C = C; g.C2 = C2; g.vseqf = vs;
    g.fe_acc = acc; g.mon_acc = acc + 1; g.sign = sign;
    g.rk0 = key >= 0 ? ka[key] : 0; g.rk1 = key >= 0 ? kb[key] : 0;
    g.N = N; g.K = K; g.nbx = N / 128;
    return g;
  };

  // G1: sample h (sampA), h1 probs (h1buf), cost1 -= softplus, cost2 -= h1.bh1t
  gemm_samp<F_SAMP | F_H1 | F_FE | F_DOTB>
      <<<dim3(4, M / 128), blk, 0, stream>>>(
      mk(vseq_bf, BTw1, OFF_BH1, sampA, h1buf, nullptr, 1.0f, 0, NH, NV));

  // 10 paired dispatches: RBM1 chain (z=0) + RBM2 chain (z=1)
  dim3 pg(4, M / 128, 2);
  GemmArgs V[5], Hh[4], A2g[5], B2g[5];
  for (int it = 0; it < 5; it++) {
    if (it > 0)
      Hh[it - 1] = mk(sampB, BTw1, OFF_BH1, sampA, nullptr, nullptr, 0.f,
                      2 * it, NH, NV);
    V[it] = mk(sampA, BTw1t, OFF_BV, sampB, nullptr,
               (it == 4 || it == 0) ? v_seq : nullptr,
               (it == 4) ? -1.0f : (it == 0) ? 1.0f : 0.f,
               2 * it + 1, NV, NH);
    A2g[it] = mk((it == 0) ? h1buf : sampD,
                 BTw2, OFF_BH2, sampC, nullptr, nullptr,
                 (it == 0) ? 1.0f : 0.f, 10 + 2 * it, NH, NH);
    B2g[it] = mk(sampC, BTw2t, OFF_BH1, sampD, nullptr, nullptr,
                 (it == 4) ? -1.0f : 0.f, 11 + 2 * it, NH, NH);
  }
  GemmArgs FE1 = mk(sampB, BTw1, OFF_BH1, nullptr, nullptr, nullptr, -1.0f,
                    -1, NH, NV);
  GemmArgs FE2 = mk(sampD, BTw2, OFF_BH2, nullptr, nullptr, nullptr, -1.0f,
                    -1, NH, NH);

  // V[0] carries F_DOTV: its K-ext accB IS bv_t -> cost1 -= v_seq . bv_t
  gemm_pair<F_SAMP | F_DOTV, F_SAMP | F_FE>
      <<<pg, blk, 0, stream>>>(V[0], A2g[0]);   // A2g[0]: A=h1buf
  gemm_pair<F_SAMP, F_SAMP>
      <<<pg, blk, 0, stream>>>(Hh[0], B2g[0]);
  gemm_pair<F_SAMP, F_SAMP>
      <<<pg, blk, 0, stream>>>(V[1], A2g[1]);
  gemm_pair<F_SAMP, F_SAMP>
      <<<pg, blk, 0, stream>>>(Hh[1], B2g[1]);
  gemm_pair<F_SAMP, F_SAMP>
      <<<pg, blk, 0, stream>>>(V[2], A2g[2]);
  gemm_pair<F_SAMP, F_SAMP>
      <<<pg, blk, 0, stream>>>(Hh[2], B2g[2]);
  gemm_pair<F_SAMP, F_SAMP>
      <<<pg, blk, 0, stream>>>(V[3], A2g[3]);
  gemm_pair<F_SAMP, F_SAMP>
      <<<pg, blk, 0, stream>>>(Hh[3], B2g[3]);
  gemm_pair<F_SAMP | F_MON | F_DOTS, F_SAMP>
      <<<pg, blk, 0, stream>>>(V[4], A2g[4]);
  gemm_pair<F_FE, F_SAMP | F_DOTS>
      <<<pg, blk, 0, stream>>>(FE1, B2g[4]);

  // FE2(sample): cost2 += softplus(h1s@W2 + bh2t)
  gemm_samp<F_FE><<<dim3(4, M / 128), blk, 0, stream>>>(FE2);

  finalize_kernel<<<1, 1, 0, stream>>>(acc, out);
}

// Round 7
// 1401.409 us; speedup vs baseline: 1.2506x; 1.0200x over previous
//
#include <hip/hip_runtime.h>
#include <cstdint>

#define S_LEN 32768
#define NV 256
#define NH 512
#define NR 256

typedef short bf16x8 __attribute__((ext_vector_type(8)));
typedef float f32x4 __attribute__((ext_vector_type(4)));
typedef unsigned short ushort_t;

// ---------------- bf16 helpers (bit-level, RTNE) ----------------
__device__ __forceinline__ float b2f(ushort_t u) {
  return __uint_as_float(((uint32_t)u) << 16);
}
__device__ __forceinline__ ushort_t f2b(float f) {
  uint32_t x = __float_as_uint(f);
  uint32_t r = (x + 0x7fffu + ((x >> 16) & 1u)) >> 16;
  return (ushort_t)r;
}

// ---------------- async global->LDS staging ----------------
// R21: R6 cut traffic 183->70MB/pair (bias_cat gone) but VGPR blew up 88->196
// on ALL instantiations (occupancy 20->9.3%, dur 166->207): the VALU-computed
// swizzle coords pushed every derived address chain into VGPRs, and the
// by-reference accumulator param perturbed regalloc. Fix: readfirstlane the
// wave-uniform swizzle coords back to SGPRs; R4-style captured-acc lambdas
// (computeA/computeB from one macro), accB only touched under constexpr HASB.
#define GLOAD_LDS16(gsrc, ldst)                                        \
  __builtin_amdgcn_global_load_lds(                                    \
      (const __attribute__((address_space(1))) void*)(gsrc),           \
      (__attribute__((address_space(3))) void*)(ldst), 16, 0, 0)

// ---------------- host threefry2x32 (key-chain derivation) ----------------
#define TFR(x0,x1,r) { x0 += x1; x1 = ((x1 << (r)) | (x1 >> (32 - (r)))); x1 ^= x0; }
__host__ __forceinline__ void tf2x32(uint32_t k0, uint32_t k1,
                                     uint32_t x0, uint32_t x1,
                                     uint32_t* o0, uint32_t* o1) {
  uint32_t k2 = k0 ^ k1 ^ 0x1BD11BDAu;
  x0 += k0; x1 += k1;
  TFR(x0,x1,13) TFR(x0,x1,15) TFR(x0,x1,26) TFR(x0,x1,6)
  x0 += k1; x1 += k2 + 1u;
  TFR(x0,x1,17) TFR(x0,x1,29) TFR(x0,x1,16) TFR(x0,x1,24)
  x0 += k2; x1 += k0 + 2u;
  TFR(x0,x1,13) TFR(x0,x1,15) TFR(x0,x1,26) TFR(x0,x1,6)
  x0 += k0; x1 += k1 + 3u;
  TFR(x0,x1,17) TFR(x0,x1,29) TFR(x0,x1,16) TFR(x0,x1,24)
  x0 += k1; x1 += k2 + 4u;
  TFR(x0,x1,13) TFR(x0,x1,15) TFR(x0,x1,26) TFR(x0,x1,6)
  x0 += k2; x1 += k0 + 5u;
  *o0 = x0; *o1 = x1;
}

// ---------------- device RNG: murmur3 full-avalanche counter hash ----------------
__device__ __forceinline__ uint32_t fast_hash(uint32_t k0, uint32_t k1, uint32_t idx) {
  uint32_t h = idx ^ k0;
  h *= 0xCC9E2D51u; h = (h << 15) | (h >> 17); h *= 0x1B873593u;
  h ^= k1;
  h ^= h >> 16; h *= 0x85EBCA6Bu;
  h ^= h >> 13; h *= 0xC2B2AE35u;
  h ^= h >> 16;
  return h;
}

__device__ __forceinline__ float wave_reduce(float v) {
#pragma unroll
  for (int o = 32; o > 0; o >>= 1) v += __shfl_down(v, o, 64);
  return v;
}
__device__ __forceinline__ float softplusf(float z) {
  return fmaxf(z, 0.f) + log1pf(expf(-fabsf(z)));
}

// ---------------- epilogue flags ----------------
#define F_SAMP  4    // Bernoulli sample -> C (bf16 0/1)
#define F_H1    8    // sigmoid -> C2 (bf16)
#define F_FE    16   // softplus sum -> fe_acc (acc += -sign*sum)
#define F_MON   32   // monitor sum vs vseqf -> mon_acc
#define F_DOTB  64   // fe_sum += p * be       (h1 . bh1t, folded into G1)
#define F_DOTS  128  // fe_sum += sample * be  (sample-side dots)
#define F_DOTV  256  // fe_sum += v_seq * be   (v_seq . bv_t, folded into V0)

struct GemmArgs {
  const ushort_t* A;    // [M,K] bf16
  const ushort_t* BT;   // [N,K] bf16
  const ushort_t* Ax;   // shifted [M,256] bf16 (bias K-extension, A side)
  const ushort_t* BXT;  // Wycat slice [N,256] bf16 (bias K-ext, B side)
  const float* bvec;    // bveccat slice (f32 per-column bias)
  ushort_t* C;          // sample out [M,N] (bf16 0/1)
  ushort_t* C2;         // sigmoid out (F_H1, bf16)
  const float* vseqf;   // f32 v_seq (F_MON / F_DOTV)
  double* fe_acc;
  double* mon_acc;
  float sign;
  uint32_t rk0, rk1;
  int N, K, nbx;        // K = main K (ext adds 256); nbx = N/128
};

// XCD-chunked bijective swizzle. gridDim.y==256 always -> nwg%8==0; gx pow2.
// readfirstlane: values are wave-uniform; force them into SGPRs so the whole
// downstream address arithmetic stays scalar (R6's VGPR-196 lesson).
__device__ __forceinline__ void xcd_swz(int* bx, int* by) {
  const int gx = (int)gridDim.x;
  const int lin = (int)blockIdx.y * gx + (int)blockIdx.x;
  const int cpx = (gx * (int)gridDim.y) >> 3;
  const int w = (lin & 7) * cpx + (lin >> 3);
  const int lg = 31 - __clz(gx);
  *by = __builtin_amdgcn_readfirstlane(w >> lg);
  *bx = __builtin_amdgcn_readfirstlane(w & (gx - 1));
}

// One MFMA phase body over a named accumulator (R4 captured-lambda style).
#define COMPUTE_PHASE(AC, As, Bs)                                              \
  _Pragma("unroll")                                                            \
  for (int c = 0; c < 2; c++) {                                                \
    bf16x8 af[4], bf[4];                                                       \
    _Pragma("unroll")                                                          \
    for (int mt = 0; mt < 4; mt++) {                                           \
      int r = wm * 64 + mt * 16 + l16;                                         \
      af[mt] = *(const bf16x8*)&(As)[r * 64 + (((c * 4 + q) ^ (r & 7)) * 8)];  \
    }                                                                          \
    _Pragma("unroll")                                                          \
    for (int nt = 0; nt < 4; nt++) {                                           \
      int r = wn * 64 + nt * 16 + l16;                                         \
      bf[nt] = *(const bf16x8*)&(Bs)[r * 64 + (((c * 4 + q) ^ (r & 7)) * 8)];  \
    }                                                                          \
    _Pragma("unroll")                                                          \
    for (int mt = 0; mt < 4; mt++)                                             \
      _Pragma("unroll")                                                        \
      for (int nt = 0; nt < 4; nt++)                                           \
        AC[mt][nt] = __builtin_amdgcn_mfma_f32_16x16x32_bf16(                  \
            af[mt], bf[nt], AC[mt][nt], 0, 0, 0);                              \
  }

// ---------------- core GEMM body — split-acc fused-bias-K + 2-phase staging ----
template<int FLAGS>
__device__ __forceinline__ void run_gemm(const GemmArgs& g, int bx, int by,
                                         ushort_t* __restrict__ As0,
                                         ushort_t* __restrict__ As1,
                                         ushort_t* __restrict__ Bs0,
                                         ushort_t* __restrict__ Bs1) {
  constexpr bool HASB = (FLAGS & (F_DOTB | F_DOTS | F_DOTV)) != 0;
  const int tid = threadIdx.x;
  const int lane = tid & 63, wave = tid >> 6;
  const int wm = wave >> 1, wn = wave & 1;
  const int q = lane >> 4, l16 = lane & 15;
  const int m0 = by * 128, n0 = bx * 128;
  const int N = g.N, K = g.K;
  const int KT = K + 256;            // +bias extension

  f32x4 acc[4][4];
  f32x4 accB[4][4];                  // touched only under constexpr HASB
#pragma unroll
  for (int mt = 0; mt < 4; mt++)
#pragma unroll
    for (int nt = 0; nt < 4; nt++) {
      acc[mt][nt] = (f32x4){0.f, 0.f, 0.f, 0.f};
      if constexpr (HASB) accB[mt][nt] = (f32x4){0.f, 0.f, 0.f, 0.f};
    }

  auto stage = [&](ushort_t* As, ushort_t* Bs, int kks) {
    const ushort_t* Ap; const ushort_t* Bp; size_t lda; int k0;
    if (kks < K) { Ap = g.A;  Bp = g.BT;  lda = (size_t)K; k0 = kks; }
    else         { Ap = g.Ax; Bp = g.BXT; lda = 256;       k0 = kks - K; }
#pragma unroll
    for (int j = 0; j < 4; j++) {
      int c = j * 256 + tid;
      int r = c >> 3, bl = c & 7, bg = bl ^ (r & 7);
      (void)bl;
      const int ldso = (j * 256 + wave * 64) * 8;  // wave-uniform; lane adds *16B
      GLOAD_LDS16(&Ap[(size_t)(m0 + r) * lda + k0 + bg * 8], &As[ldso]);
      GLOAD_LDS16(&Bp[(size_t)(n0 + r) * lda + k0 + bg * 8], &Bs[ldso]);
    }
  };
  auto computeA = [&](const ushort_t* As, const ushort_t* Bs) {
    COMPUTE_PHASE(acc, As, Bs)
  };
  auto computeB = [&](const ushort_t* As, const ushort_t* Bs) {
    if constexpr (HASB) { COMPUTE_PHASE(accB, As, Bs) }
  };

  // 2-phase pipeline; KT in {512,768}, K%128==0 -> chunk never straddles.
  stage(As0, Bs0, 0);
  __syncthreads();
  for (int kk = 0; kk < KT; kk += 128) {
    stage(As1, Bs1, kk + 64);
    if constexpr (HASB) { if (kk >= K) computeB(As0, Bs0); else computeA(As0, Bs0); }
    else computeA(As0, Bs0);
    __syncthreads();
    if (kk + 128 < KT) stage(As0, Bs0, kk + 128);
    if constexpr (HASB) { if (kk + 64 >= K) computeB(As1, Bs1); else computeA(As1, Bs1); }
    else computeA(As1, Bs1);
    __syncthreads();
  }

  float fe_sum = 0.f, mon_sum = 0.f;
#pragma unroll
  for (int mt = 0; mt < 4; mt++) {
#pragma unroll
    for (int nt = 0; nt < 4; nt++) {
      const int gn = n0 + wn * 64 + nt * 16 + l16;
      const int gmb = m0 + wm * 64 + mt * 16 + q * 4;
      const float bvv = g.bvec[gn];
      uint32_t h0 = 0, h1 = 0;
      if constexpr (FLAGS & F_SAMP) {
        uint32_t pb = (uint32_t)((gmb >> 1) * N + gn);
        h0 = fast_hash(g.rk0, g.rk1, pb);               // rows gmb, gmb+1
        h1 = fast_hash(g.rk0, g.rk1, pb + (uint32_t)N); // rows gmb+2, gmb+3
      }
#pragma unroll
      for (int rg = 0; rg < 4; rg++) {
        const int gm = gmb + rg;
        const size_t idx = (size_t)gm * N + gn;
        float z, be = 0.f;
        if constexpr (HASB) {
          be = accB[mt][nt][rg] + bvv;   // on-the-fly bias (replaces bias_cat)
          z = acc[mt][nt][rg] + be;
        } else {
          z = acc[mt][nt][rg] + bvv;     // ext already merged into acc
        }
        if constexpr (FLAGS & F_DOTV) fe_sum += be * g.vseqf[idx];
        if constexpr (FLAGS & (F_SAMP | F_H1 | F_MON)) {
          float e = __expf(-z);
          if constexpr (FLAGS & F_SAMP) {
            uint32_t hb = (rg & 2) ? h1 : h0;
            uint32_t ub = (rg & 1) ? (hb >> 16) : (hb & 0xffffu);
            float uu = (float)ub * (1.0f / 65536.0f);
            bool sbit = fmaf(uu, e, uu) < 1.f;  // u < sigmoid(z)
            g.C[idx] = sbit ? (ushort_t)0x3f80 : (ushort_t)0;
            if constexpr (FLAGS & F_DOTS) fe_sum += sbit ? be : 0.f;
          }
          if constexpr (FLAGS & (F_H1 | F_MON)) {
            float pp = __builtin_amdgcn_rcpf(1.f + e);
            if constexpr (FLAGS & F_H1) g.C2[idx] = f2b(pp);
            if constexpr (FLAGS & F_DOTB) fe_sum += pp * be;
            if constexpr (FLAGS & F_MON) {
              float v = g.vseqf[idx];
              mon_sum += (v != 0.f) ? logf(pp + 1e-10f) : logf(1.f - pp + 1e-10f);
            }
          }
        }
        if constexpr (FLAGS & F_FE) fe_sum += softplusf(z);
      }
    }
  }
  if constexpr (FLAGS & (F_FE | F_DOTB | F_DOTS | F_DOTV)) {
    float s = wave_reduce(fe_sum);
    if (lane == 0) atomicAdd(g.fe_acc, (double)(-g.sign * s));
  }
  if constexpr (FLAGS & F_MON) {
    float s = wave_reduce(mon_sum);
    if (lane == 0) atomicAdd(g.mon_acc, (double)s);
  }
}

template<int FLAGS>
__global__ __launch_bounds__(256)
void gemm_samp(GemmArgs g) {
  __shared__ ushort_t As0[128 * 64], As1[128 * 64];
  __shared__ ushort_t Bs0[128 * 64], Bs1[128 * 64];
  int bx, by;
  xcd_swz(&bx, &by);
  if (bx >= g.nbx) return;
  run_gemm<FLAGS>(g, bx, by, As0, As1, Bs0, Bs1);
}

// Paired launch: z=0 runs g0 (RBM1 step), z=1 runs g1 (RBM2 step) — independent.
template<int F0, int F1>
__global__ __launch_bounds__(256)
void gemm_pair(GemmArgs g0, GemmArgs g1) {
  __shared__ ushort_t As0[128 * 64], As1[128 * 64];
  __shared__ ushort_t Bs0[128 * 64], Bs1[128 * 64];
  int bx, by;
  xcd_swz(&bx, &by);
  if (blockIdx.z == 0) {
    if (bx >= g0.nbx) return;
    run_gemm<F0>(g0, bx, by, As0, As1, Bs0, Bs1);
  } else {
    if (bx >= g1.nbx) return;
    run_gemm<F1>(g1, bx, by, As0, As1, Bs0, Bs1);
  }
}

// ---------------- plain GEMM + f32-vector bias (Arnn pre-activation) ------------
__global__ __launch_bounds__(256)
void gemm_bias(const ushort_t* __restrict__ A, const ushort_t* __restrict__ BT,
               const float* __restrict__ biasv, float* __restrict__ Cf,
               int M, int N, int K) {
  __shared__ ushort_t As0[128 * 64], As1[128 * 64];
  __shared__ ushort_t Bs0[128 * 64], Bs1[128 * 64];
  const int tid = threadIdx.x;
  const int lane = tid & 63, wave = tid >> 6;
  const int wm = wave >> 1, wn = wave & 1;
  const int q = lane >> 4, l16 = lane & 15;
  int bx, by;
  xcd_swz(&bx, &by);
  const int m0 = by * 128, n0 = bx * 128;
  (void)lane;

  f32x4 acc[4][4];
#pragma unroll
  for (int i = 0; i < 4; i++)
#pragma unroll
    for (int j = 0; j < 4; j++) acc[i][j] = (f32x4){0.f, 0.f, 0.f, 0.f};

  auto stage = [&](ushort_t* As, ushort_t* Bs, int kk) {
#pragma unroll
    for (int j = 0; j < 4; j++) {
      int c = j * 256 + tid;
      int r = c >> 3, bl = c & 7, bg = bl ^ (r & 7);
      (void)bl;
      const int ldso = (j * 256 + wave * 64) * 8;
      GLOAD_LDS16(&A[(size_t)(m0 + r) * K + kk + bg * 8], &As[ldso]);
      GLOAD_LDS16(&BT[(size_t)(n0 + r) * K + kk + bg * 8], &Bs[ldso]);
    }
  };
  auto compute = [&](const ushort_t* As, const ushort_t* Bs) {
    COMPUTE_PHASE(acc, As, Bs)
  };

  stage(As0, Bs0, 0);
  __syncthreads();
  for (int kk = 0; kk < K; kk += 128) {
    stage(As1, Bs1, kk + 64);
    compute(As0, Bs0);
    __syncthreads();
    if (kk + 128 < K) stage(As0, Bs0, kk + 128);
    compute(As1, Bs1);
    __syncthreads();
  }

#pragma unroll
  for (int mt = 0; mt < 4; mt++)
#pragma unroll
    for (int nt = 0; nt < 4; nt++) {
      const int gn = n0 + wn * 64 + nt * 16 + l16;
      const int gmb = m0 + wm * 64 + mt * 16 + q * 4;
      const float bvv = biasv[gn];
#pragma unroll
      for (int rg = 0; rg < 4; rg++)
        Cf[(size_t)(gmb + rg) * N + gn] = acc[mt][nt][rg] + bvv;
    }
}

// ---------------- chunked RNN scan v5 (R10-proven) ----------------
__global__ __launch_bounds__(1024, 1)
void rnn_scan(const float* __restrict__ Apre, const float* __restrict__ Wuu,
              ushort_t* __restrict__ shifted) {
  const int tid = threadIdx.x;
  const int j = tid >> 2;
  const int s = tid & 3;
  const int t_begin = blockIdx.x * 128;
  const int t_end = t_begin + 128;
  const int t0 = (t_begin >= 16) ? (t_begin - 16) : 0;

  float w[64];
#pragma unroll
  for (int i = 0; i < 64; i++) w[i] = Wuu[(size_t)(s * 64 + i) * 256 + j];

  __shared__ float u[2][280];
  __shared__ float asg[32 * 256];
  if (tid < 256) u[0][(tid >> 6) * 68 + (tid & 63)] = 0.f;
  if (blockIdx.x == 0 && s == 0) shifted[j] = 0;
  __syncthreads();

  const int jp = (j >> 6) * 68 + (j & 63);
  int p = 0;
  for (int tb = t0; tb < t_end; tb += 32) {
    int srow = tb + (tid >> 5);
    if (srow >= S_LEN) srow = S_LEN - 1;
    int scol = (tid & 31) * 8;
    float4 a0 = *(const float4*)&Apre[(size_t)srow * 256 + scol];
    float4 a1 = *(const float4*)&Apre[(size_t)srow * 256 + scol + 4];
    *(float4*)&asg[(tid >> 5) * 256 + scol] = a0;
    *(float4*)&asg[(tid >> 5) * 256 + scol + 4] = a1;
    __syncthreads();
#pragma unroll 1
    for (int i = 0; i < 32; i++) {
      const int t = tb + i;
      if (t >= t_end) break;
      float p0 = 0.f, p1 = 0.f, p2 = 0.f, p3 = 0.f;
#pragma unroll
      for (int qq = 0; qq < 64; qq += 4) {
        float4 uv = *(const float4*)&u[p][s * 68 + qq];
        p0 = fmaf(uv.x, w[qq + 0], p0);
        p1 = fmaf(uv.y, w[qq + 1], p1);
        p2 = fmaf(uv.z, w[qq + 2], p2);
        p3 = fmaf(uv.w, w[qq + 3], p3);
      }
      float ps = (p0 + p1) + (p2 + p3);
      ps += __shfl_xor(ps, 1, 64);
      ps += __shfl_xor(ps, 2, 64);
      float z = asg[i * 256 + j] + ps;
      float e = __expf(2.f * z);
      float unew = 1.f - 2.f * __builtin_amdgcn_rcpf(e + 1.f);
      if (s == 0) {
        u[1 - p][jp] = unew;
        if (t >= t_begin && (t + 1) < S_LEN)
          shifted[(size_t)(t + 1) * 256 + j] = f2b(unew);
      }
      __syncthreads();
      p ^= 1;
    }
  }
}

// ---------------- single prep kernel ----------------
__global__ __launch_bounds__(256)
void prep_all(const float* __restrict__ v_seq, ushort_t* __restrict__ vseq_bf,
              const float* __restrict__ Wyv, const float* __restrict__ Wyh1,
              const float* __restrict__ Wyh2, ushort_t* __restrict__ Wycat,
              const float* __restrict__ W1, ushort_t* __restrict__ BTw1t,
              ushort_t* __restrict__ BTw1,
              const float* __restrict__ W2, ushort_t* __restrict__ BTw2t,
              ushort_t* __restrict__ BTw2,
              const float* __restrict__ Wvu, ushort_t* __restrict__ BTwvu,
              const float* __restrict__ bv, const float* __restrict__ bh1,
              const float* __restrict__ bh2, float* __restrict__ bveccat) {
  int b = blockIdx.x;
  const int tid = threadIdx.x;
  if (b < 32768) { int i = b * 256 + tid; vseq_bf[i] = f2b(v_seq[i]); return; }
  b -= 32768;
  if (b < 256)  { int i = b * 256 + tid; Wycat[i] = f2b(Wyv[i]); return; }
  b -= 256;
  if (b < 512)  { int i = b * 256 + tid; Wycat[65536 + i] = f2b(Wyh1[i]); return; }
  b -= 512;
  if (b < 512)  { int i = b * 256 + tid; Wycat[196608 + i] = f2b(Wyh2[i]); return; }
  b -= 512;
  if (b < 512)  { int i = b * 256 + tid; BTw1t[i] = f2b(W1[i]); return; }
  b -= 512;
  if (b < 1024) { int i = b * 256 + tid; BTw2t[i] = f2b(W2[i]); return; }
  b -= 1024;
  if (b < 256)  { int i = b * 256 + tid; int r = i >> 8, c = i & 255;
                  BTwvu[c * 256 + r] = f2b(Wvu[i]); return; }
  b -= 256;
  if (b < 512)  { int i = b * 256 + tid; int r = i >> 9, c = i & 511;
                  BTw1[(size_t)c * 256 + r] = f2b(W1[i]); return; }
  b -= 512;
  if (b < 1024) { int i = b * 256 + tid; int r = i >> 9, c = i & 511;
                  BTw2[(size_t)c * 512 + r] = f2b(W2[i]); return; }
  b -= 1024;
  { int i = b * 256 + tid;
    if (i < 1280)
      bveccat[i] = (i < 256) ? bv[i] : (i < 768) ? bh1[i - 256] : bh2[i - 768]; }
}

__global__ void finalize_kernel(const double* __restrict__ acc, float* __restrict__ out) {
  out[0] = (float)(acc[0] / (double)S_LEN);
  out[1] = (float)(acc[1] / (double)S_LEN);
}

// ---------------- host orchestration ----------------
extern "C" void kernel_launch(void* const* d_in, const int* in_sizes, int n_in,
                              void* d_out, int out_size, void* d_ws, size_t ws_size,
                              hipStream_t stream) {
  (void)in_sizes; (void)n_in; (void)out_size; (void)ws_size;
  const float* v_seq = (const float*)d_in[0];
  const float* W1    = (const float*)d_in[1];
  const float* bv    = (const float*)d_in[2];
  const float* bh1   = (const float*)d_in[3];
  const float* W2    = (const float*)d_in[4];
  const float* bh2   = (const float*)d_in[5];
  const float* Wyv   = (const float*)d_in[6];
  const float* Wyh1  = (const float*)d_in[7];
  const float* Wyh2  = (const float*)d_in[8];
  const float* Wvu   = (const float*)d_in[9];
  const float* Wuu   = (const float*)d_in[10];
  const float* bu    = (const float*)d_in[11];
  float* out = (float*)d_out;

  const size_t SN = (size_t)S_LEN * NV;   // 8.4M
  const size_t SH = (size_t)S_LEN * NH;   // 16.8M
  char* base = (char*)d_ws;
  size_t cur = 0;
  auto take = [&](size_t bytes) { size_t o = cur; cur += (bytes + 255) & ~(size_t)255; return o; };
  double*   acc      = (double*)  (base + take(64));
  ushort_t* BTwvu    = (ushort_t*)(base + take(65536 * 2));
  ushort_t* Wycat    = (ushort_t*)(base + take((size_t)1280 * NR * 2));
  float*    bveccat  = (float*)   (base + take(1280 * 4));
  ushort_t* BTw1     = (ushort_t*)(base + take(131072 * 2));   // W1^T [512,256]
  ushort_t* BTw1t    = (ushort_t*)(base + take(131072 * 2));   // W1   [256,512]
  ushort_t* BTw2     = (ushort_t*)(base + take(262144 * 2));   // W2^T [512,512]
  ushort_t* BTw2t    = (ushort_t*)(base + take(262144 * 2));   // W2   [512,512]
  ushort_t* vseq_bf  = (ushort_t*)(base + take(SN * 2));
  ushort_t* shifted  = (ushort_t*)(base + take(SN * 2));
  float*    Arnn     = (float*)   (base + take(SN * 4));       // RNN pre-activation
  ushort_t* h1buf    = (ushort_t*)(base + take(SH * 2));       // h1 probs / sampD
  ushort_t* sampA    = (ushort_t*)(base + take(SH * 2));       // RBM1 h samples
  ushort_t* sampB    = (ushort_t*)(base + take(SN * 2));       // RBM1 v samples
  ushort_t* sampC    = (ushort_t*)(base + take(SH * 2));       // RBM2 h2 samples
  ushort_t* sampD = h1buf;   // alias: h1buf last read (A2g[0]) before sampD write

  uint32_t ka[20], kb[20];
  uint32_t K0 = 0u, K1 = 42u;
  for (int it = 0; it < 10; it++) {
    uint32_t n0, n1, a0, a1, b0, b1;
    tf2x32(K0, K1, 0u, 0u, &n0, &n1);
    tf2x32(K0, K1, 0u, 1u, &a0, &a1);
    tf2x32(K0, K1, 0u, 2u, &b0, &b1);
    ka[2 * it] = a0; kb[2 * it] = a1;
    ka[2 * it + 1] = b0; kb[2 * it + 1] = b1;
    K0 = n0; K1 = n1;
  }

  hipMemsetAsync(acc, 0, 2 * sizeof(double), stream);

  dim3 blk(256);
  prep_all<<<dim3(37381), blk, 0, stream>>>(
      v_seq, vseq_bf, Wyv, Wyh1, Wyh2, Wycat, W1, BTw1t, BTw1,
      W2, BTw2t, BTw2, Wvu, BTwvu, bv, bh1, bh2, bveccat);

  const int M = S_LEN;
  gemm_bias<<<dim3(2, M / 128), blk, 0, stream>>>(
      vseq_bf, BTwvu, bu, Arnn, M, NV, NV);
  rnn_scan<<<dim3(S_LEN / 128), dim3(1024), 0, stream>>>(Arnn, Wuu, shifted);

  const int OFF_BV = 0, OFF_BH1 = NV, OFF_BH2 = NV + NH;
  auto mk = [&](const ushort_t* A, const ushort_t* BT, int boff, ushort_t* C,
                ushort_t* C2, const float* vs, float sign, int key, int N, int K) {
    GemmArgs g;
    g.A = A; g.BT = BT;
    g.Ax = shifted;
    g.BXT = Wycat + (size_t)boff * 256;
    g.bvec = bveccat + boff;
    g.C = C; g.C2 = C2; g.vseqf = vs;
    g.fe_acc = acc; g.mon_acc = acc + 1; g.sign = sign;
    g.rk0 = key >= 0 ? ka[key] : 0; g.rk1 = key >= 0 ? kb[key] : 0;
    g.N = N; g.K = K; g.nbx = N / 128;
    return g;
  };

  // G1: sample h (sampA), h1 probs (h1buf), cost1 -= softplus, cost2 -= h1.bh1t
  gemm_samp<F_SAMP | F_H1 | F_FE | F_DOTB>
      <<<dim3(4, M / 128), blk, 0, stream>>>(
      mk(vseq_bf, BTw1, OFF_BH1, sampA, h1buf, nullptr, 1.0f, 0, NH, NV));

  // 10 paired dispatches: RBM1 chain (z=0) + RBM2 chain (z=1)
  dim3 pg(4, M / 128, 2);
  GemmArgs V[5], Hh[4], A2g[5], B2g[5];
  for (int it = 0; it < 5; it++) {
    if (it > 0)
      Hh[it - 1] = mk(sampB, BTw1, OFF_BH1, sampA, nullptr, nullptr, 0.f,
                      2 * it, NH, NV);
    V[it] = mk(sampA, BTw1t, OFF_BV, sampB, nullptr,
               (it == 4 || it == 0) ? v_seq : nullptr,
               (it == 4) ? -1.0f : (it == 0) ? 1.0f : 0.f,
               2 * it + 1, NV, NH);
    A2g[it] = mk((it == 0) ? h1buf : sampD,
                 BTw2, OFF_BH2, sampC, nullptr, nullptr,
                 (it == 0) ? 1.0f : 0.f, 10 + 2 * it, NH, NH);
    B2g[it] = mk(sampC, BTw2t, OFF_BH1, sampD, nullptr, nullptr,
                 (it == 4) ? -1.0f : 0.f, 11 + 2 * it, NH, NH);
  }
  GemmArgs FE1 = mk(sampB, BTw1, OFF_BH1, nullptr, nullptr, nullptr, -1.0f,
                    -1, NH, NV);
  GemmArgs FE2 = mk(sampD, BTw2, OFF_BH2, nullptr, nullptr, nullptr, -1.0f,
                    -1, NH, NH);

  // V[0] carries F_DOTV: its K-ext accB IS bv_t -> cost1 -= v_seq . bv_t
  gemm_pair<F_SAMP | F_DOTV, F_SAMP | F_FE>
      <<<pg, blk, 0, stream>>>(V[0], A2g[0]);   // A2g[0]: A=h1buf
  gemm_pair<F_SAMP, F_SAMP>
      <<<pg, blk, 0, stream>>>(Hh[0], B2g[0]);
  gemm_pair<F_SAMP, F_SAMP>
      <<<pg, blk, 0, stream>>>(V[1], A2g[1]);
  gemm_pair<F_SAMP, F_SAMP>
      <<<pg, blk, 0, stream>>>(Hh[1], B2g[1]);
  gemm_pair<F_SAMP, F_SAMP>
      <<<pg, blk, 0, stream>>>(V[2], A2g[2]);
  gemm_pair<F_SAMP, F_SAMP>
      <<<pg, blk, 0, stream>>>(Hh[2], B2g[2]);
  gemm_pair<F_SAMP, F_SAMP>
      <<<pg, blk, 0, stream>>>(V[3], A2g[3]);
  gemm_pair<F_SAMP, F_SAMP>
      <<<pg, blk, 0, stream>>>(Hh[3], B2g[3]);
  gemm_pair<F_SAMP | F_MON | F_DOTS, F_SAMP>
      <<<pg, blk, 0, stream>>>(V[4], A2g[4]);
  gemm_pair<F_FE, F_SAMP | F_DOTS>
      <<<pg, blk, 0, stream>>>(FE1, B2g[4]);

  // FE2(sample): cost2 += softplus(h1s@W2 + bh2t)
  gemm_samp<F_FE><<<dim3(4, M / 128), blk, 0, stream>>>(FE2);

  finalize_kernel<<<1, 1, 0, stream>>>(acc, out);
}

// Round 8
// 1186.906 us; speedup vs baseline: 1.4766x; 1.1807x over previous
//
#include <hip/hip_runtime.h>
#include <cstdint>

#define S_LEN 32768
#define NV 256
#define NH 512
#define NR 256

typedef short bf16x8 __attribute__((ext_vector_type(8)));
typedef float f32x4 __attribute__((ext_vector_type(4)));
typedef unsigned short ushort_t;

// ---------------- bf16 helpers (bit-level, RTNE) ----------------
__device__ __forceinline__ float b2f(ushort_t u) {
  return __uint_as_float(((uint32_t)u) << 16);
}
__device__ __forceinline__ ushort_t f2b(float f) {
  uint32_t x = __float_as_uint(f);
  uint32_t r = (x + 0x7fffu + ((x >> 16) & 1u)) >> 16;
  return (ushort_t)r;
}

// ---------------- async global->LDS staging ----------------
// R22: R7 showed the accB split-accumulator (128 VGPR of acc alone) pinned the
// DOT-bearing GEMMs at 196 VGPR / 9.4% occupancy -> effective BW ~580 GB/s.
// Fix: move ALL bias-dot terms into 2 cheap standalone kernels at the end
// (fe += (X1-X2) . (shifted@Wy^T + b), K=256). Chain GEMMs revert to the
// single merged accumulator (R4's 88-VGPR shape, no bias_cat reads), LDS
// single-buffer 32KB, flattened pair grids (no dead blocks), bijective XCD
// swizzle. Goal: R7's 70MB/pair traffic at >=R4's 20% occupancy.
#define GLOAD_LDS16(gsrc, ldst)                                        \
  __builtin_amdgcn_global_load_lds(                                    \
      (const __attribute__((address_space(1))) void*)(gsrc),           \
      (__attribute__((address_space(3))) void*)(ldst), 16, 0, 0)

// ---------------- host threefry2x32 (key-chain derivation) ----------------
#define TFR(x0,x1,r) { x0 += x1; x1 = ((x1 << (r)) | (x1 >> (32 - (r)))); x1 ^= x0; }
__host__ __forceinline__ void tf2x32(uint32_t k0, uint32_t k1,
                                     uint32_t x0, uint32_t x1,
                                     uint32_t* o0, uint32_t* o1) {
  uint32_t k2 = k0 ^ k1 ^ 0x1BD11BDAu;
  x0 += k0; x1 += k1;
  TFR(x0,x1,13) TFR(x0,x1,15) TFR(x0,x1,26) TFR(x0,x1,6)
  x0 += k1; x1 += k2 + 1u;
  TFR(x0,x1,17) TFR(x0,x1,29) TFR(x0,x1,16) TFR(x0,x1,24)
  x0 += k2; x1 += k0 + 2u;
  TFR(x0,x1,13) TFR(x0,x1,15) TFR(x0,x1,26) TFR(x0,x1,6)
  x0 += k0; x1 += k1 + 3u;
  TFR(x0,x1,17) TFR(x0,x1,29) TFR(x0,x1,16) TFR(x0,x1,24)
  x0 += k1; x1 += k2 + 4u;
  TFR(x0,x1,13) TFR(x0,x1,15) TFR(x0,x1,26) TFR(x0,x1,6)
  x0 += k2; x1 += k0 + 5u;
  *o0 = x0; *o1 = x1;
}

// ---------------- device RNG: murmur3 full-avalanche counter hash ----------------
__device__ __forceinline__ uint32_t fast_hash(uint32_t k0, uint32_t k1, uint32_t idx) {
  uint32_t h = idx ^ k0;
  h *= 0xCC9E2D51u; h = (h << 15) | (h >> 17); h *= 0x1B873593u;
  h ^= k1;
  h ^= h >> 16; h *= 0x85EBCA6Bu;
  h ^= h >> 13; h *= 0xC2B2AE35u;
  h ^= h >> 16;
  return h;
}

__device__ __forceinline__ float wave_reduce(float v) {
#pragma unroll
  for (int o = 32; o > 0; o >>= 1) v += __shfl_down(v, o, 64);
  return v;
}
__device__ __forceinline__ float softplusf(float z) {
  return fmaxf(z, 0.f) + log1pf(expf(-fabsf(z)));
}

// ---------------- epilogue flags ----------------
#define F_SAMP  4    // Bernoulli sample -> C (bf16 0/1)
#define F_H1    8    // sigmoid -> C2 (bf16)
#define F_FE    16   // softplus sum -> fe_acc (acc += -sign*sum)
#define F_MON   32   // monitor sum vs vseqf -> mon_acc

struct GemmArgs {
  const ushort_t* A;    // [M,K] bf16
  const ushort_t* BT;   // [N,K] bf16
  const ushort_t* Ax;   // shifted [M,256] bf16 (bias K-extension, A side)
  const ushort_t* BXT;  // Wycat slice [N,256] bf16 (bias K-ext, B side)
  const float* bvec;    // bveccat slice (f32 per-column bias)
  ushort_t* C;          // sample out [M,N] (bf16 0/1)
  ushort_t* C2;         // sigmoid out (F_H1, bf16)
  const float* vseqf;   // f32 v_seq (F_MON)
  double* fe_acc;
  double* mon_acc;
  float sign;
  uint32_t rk0, rk1;
  int N, K, nbx;        // K = main K (ext adds 256); nbx = N/128
};

// Bijective XCD-chunk swizzle for arbitrary gx (nwg = gx*256, %8==0 always).
// Inputs are blockIdx (SGPR); readfirstlane pins results scalar.
__device__ __forceinline__ void xcd_swz(int* bx, int* by) {
  const int gx = (int)gridDim.x;
  const int lin = (int)blockIdx.y * gx + (int)blockIdx.x;
  const int cpx = (gx << 8) >> 3;              // gridDim.y == 256 always
  const int w = (lin & 7) * cpx + (lin >> 3);
  const int byv = w / gx;
  *by = __builtin_amdgcn_readfirstlane(byv);
  *bx = __builtin_amdgcn_readfirstlane(w - byv * gx);
}

// ---------------- core GEMM body — merged-acc fused-bias-K, single-buffer ----
template<int FLAGS>
__device__ __forceinline__ void run_gemm(const GemmArgs& g, int bx, int by,
                                         ushort_t* __restrict__ As,
                                         ushort_t* __restrict__ Bs) {
  const int tid = threadIdx.x;
  const int lane = tid & 63, wave = tid >> 6;
  const int wm = wave >> 1, wn = wave & 1;
  const int q = lane >> 4, l16 = lane & 15;
  const int m0 = by * 128, n0 = bx * 128;
  const int N = g.N, K = g.K;
  const int KT = K + 256;            // +bias extension

  f32x4 acc[4][4];
#pragma unroll
  for (int mt = 0; mt < 4; mt++)
#pragma unroll
    for (int nt = 0; nt < 4; nt++) acc[mt][nt] = (f32x4){0.f, 0.f, 0.f, 0.f};

  for (int kk = 0; kk < KT; kk += 64) {
    const ushort_t* Ap; const ushort_t* Bp; size_t lda; int k0;
    if (kk < K) { Ap = g.A;  Bp = g.BT;  lda = (size_t)K; k0 = kk; }
    else        { Ap = g.Ax; Bp = g.BXT; lda = 256;       k0 = kk - K; }
#pragma unroll
    for (int j = 0; j < 4; j++) {
      int c = j * 256 + tid;
      int r = c >> 3, bg = (c & 7) ^ (r & 7);
      const int ldso = (j * 256 + wave * 64) * 8;  // wave-uniform; lane adds *16B
      GLOAD_LDS16(&Ap[(size_t)(m0 + r) * lda + k0 + bg * 8], &As[ldso]);
      GLOAD_LDS16(&Bp[(size_t)(n0 + r) * lda + k0 + bg * 8], &Bs[ldso]);
    }
    __syncthreads();
#pragma unroll
    for (int c = 0; c < 2; c++) {
      bf16x8 af[4], bf[4];
#pragma unroll
      for (int mt = 0; mt < 4; mt++) {
        int r = wm * 64 + mt * 16 + l16;
        af[mt] = *(const bf16x8*)&As[r * 64 + (((c * 4 + q) ^ (r & 7)) * 8)];
      }
#pragma unroll
      for (int nt = 0; nt < 4; nt++) {
        int r = wn * 64 + nt * 16 + l16;
        bf[nt] = *(const bf16x8*)&Bs[r * 64 + (((c * 4 + q) ^ (r & 7)) * 8)];
      }
#pragma unroll
      for (int mt = 0; mt < 4; mt++)
#pragma unroll
        for (int nt = 0; nt < 4; nt++)
          acc[mt][nt] = __builtin_amdgcn_mfma_f32_16x16x32_bf16(
              af[mt], bf[nt], acc[mt][nt], 0, 0, 0);
    }
    __syncthreads();
  }

  float fe_sum = 0.f, mon_sum = 0.f;
#pragma unroll
  for (int mt = 0; mt < 4; mt++) {
#pragma unroll
    for (int nt = 0; nt < 4; nt++) {
      const int gn = n0 + wn * 64 + nt * 16 + l16;
      const int gmb = m0 + wm * 64 + mt * 16 + q * 4;
      const float bvv = g.bvec[gn];
      uint32_t h0 = 0, h1 = 0;
      if constexpr (FLAGS & F_SAMP) {
        uint32_t pb = (uint32_t)((gmb >> 1) * N + gn);
        h0 = fast_hash(g.rk0, g.rk1, pb);               // rows gmb, gmb+1
        h1 = fast_hash(g.rk0, g.rk1, pb + (uint32_t)N); // rows gmb+2, gmb+3
      }
#pragma unroll
      for (int rg = 0; rg < 4; rg++) {
        const int gm = gmb + rg;
        const size_t idx = (size_t)gm * N + gn;
        float z = acc[mt][nt][rg] + bvv;   // matrix bias merged via K-ext
        if constexpr (FLAGS & (F_SAMP | F_H1 | F_MON)) {
          float e = __expf(-z);
          if constexpr (FLAGS & F_SAMP) {
            uint32_t hb = (rg & 2) ? h1 : h0;
            uint32_t ub = (rg & 1) ? (hb >> 16) : (hb & 0xffffu);
            float uu = (float)ub * (1.0f / 65536.0f);
            bool sbit = fmaf(uu, e, uu) < 1.f;  // u < sigmoid(z)
            g.C[idx] = sbit ? (ushort_t)0x3f80 : (ushort_t)0;
          }
          if constexpr (FLAGS & (F_H1 | F_MON)) {
            float pp = __builtin_amdgcn_rcpf(1.f + e);
            if constexpr (FLAGS & F_H1) g.C2[idx] = f2b(pp);
            if constexpr (FLAGS & F_MON) {
              float v = g.vseqf[idx];
              mon_sum += (v != 0.f) ? logf(pp + 1e-10f) : logf(1.f - pp + 1e-10f);
            }
          }
        }
        if constexpr (FLAGS & F_FE) fe_sum += softplusf(z);
      }
    }
  }
  if constexpr (FLAGS & F_FE) {
    float s = wave_reduce(fe_sum);
    if (lane == 0) atomicAdd(g.fe_acc, (double)(-g.sign * s));
  }
  if constexpr (FLAGS & F_MON) {
    float s = wave_reduce(mon_sum);
    if (lane == 0) atomicAdd(g.mon_acc, (double)s);
  }
}

template<int FLAGS>
__global__ __launch_bounds__(256)
void gemm_samp(GemmArgs g) {
  __shared__ ushort_t As[128 * 64];
  __shared__ ushort_t Bs[128 * 64];
  int bx, by;
  xcd_swz(&bx, &by);
  if (bx >= g.nbx) return;
  run_gemm<FLAGS>(g, bx, by, As, Bs);
}

// Flattened pair: gridDim.x = g0.nbx + g1.nbx (no dead blocks, no z dim).
template<int F0, int F1>
__global__ __launch_bounds__(256)
void gemm_pair(GemmArgs g0, GemmArgs g1) {
  __shared__ ushort_t As[128 * 64];
  __shared__ ushort_t Bs[128 * 64];
  int bx, by;
  xcd_swz(&bx, &by);
  if (bx < g0.nbx) {
    run_gemm<F0>(g0, bx, by, As, Bs);
  } else {
    run_gemm<F1>(g1, bx - g0.nbx, by, As, Bs);
  }
}

// ---------------- bias-dot kernel: fe += sum (X1-X2) . (Ash@BXT^T + bvec) ----
// Ash = shifted [S,256], BXT = Wycat slice [N,256], K=256. X1 bf16; X2 f32
// (v_seq) or bf16 (h1 probs).
template<bool X2F32>
__global__ __launch_bounds__(256)
void dot_bias(const ushort_t* __restrict__ Ash, const ushort_t* __restrict__ BXT,
              const float* __restrict__ bvec, const ushort_t* __restrict__ X1,
              const void* __restrict__ X2, double* __restrict__ fe_acc, int N) {
  __shared__ ushort_t As[128 * 64];
  __shared__ ushort_t Bs[128 * 64];
  const int tid = threadIdx.x;
  const int lane = tid & 63, wave = tid >> 6;
  const int wm = wave >> 1, wn = wave & 1;
  const int q = lane >> 4, l16 = lane & 15;
  int bx, by;
  xcd_swz(&bx, &by);
  const int m0 = by * 128, n0 = bx * 128;

  f32x4 acc[4][4];
#pragma unroll
  for (int i = 0; i < 4; i++)
#pragma unroll
    for (int j = 0; j < 4; j++) acc[i][j] = (f32x4){0.f, 0.f, 0.f, 0.f};

  for (int kk = 0; kk < 256; kk += 64) {
#pragma unroll
    for (int j = 0; j < 4; j++) {
      int c = j * 256 + tid;
      int r = c >> 3, bg = (c & 7) ^ (r & 7);
      const int ldso = (j * 256 + wave * 64) * 8;
      GLOAD_LDS16(&Ash[(size_t)(m0 + r) * 256 + kk + bg * 8], &As[ldso]);
      GLOAD_LDS16(&BXT[(size_t)(n0 + r) * 256 + kk + bg * 8], &Bs[ldso]);
    }
    __syncthreads();
#pragma unroll
    for (int c = 0; c < 2; c++) {
      bf16x8 af[4], bf[4];
#pragma unroll
      for (int mt = 0; mt < 4; mt++) {
        int r = wm * 64 + mt * 16 + l16;
        af[mt] = *(const bf16x8*)&As[r * 64 + (((c * 4 + q) ^ (r & 7)) * 8)];
      }
#pragma unroll
      for (int nt = 0; nt < 4; nt++) {
        int r = wn * 64 + nt * 16 + l16;
        bf[nt] = *(const bf16x8*)&Bs[r * 64 + (((c * 4 + q) ^ (r & 7)) * 8)];
      }
#pragma unroll
      for (int mt = 0; mt < 4; mt++)
#pragma unroll
        for (int nt = 0; nt < 4; nt++)
          acc[mt][nt] = __builtin_amdgcn_mfma_f32_16x16x32_bf16(
              af[mt], bf[nt], acc[mt][nt], 0, 0, 0);
    }
    __syncthreads();
  }

  float fe_sum = 0.f;
#pragma unroll
  for (int mt = 0; mt < 4; mt++)
#pragma unroll
    for (int nt = 0; nt < 4; nt++) {
      const int gn = n0 + wn * 64 + nt * 16 + l16;
      const int gmb = m0 + wm * 64 + mt * 16 + q * 4;
      const float bvv = bvec[gn];
#pragma unroll
      for (int rg = 0; rg < 4; rg++) {
        const size_t idx = (size_t)(gmb + rg) * N + gn;
        float be = acc[mt][nt][rg] + bvv;
        float x1 = b2f(X1[idx]);
        float x2 = X2F32 ? ((const float*)X2)[idx]
                         : b2f(((const ushort_t*)X2)[idx]);
        fe_sum += be * (x1 - x2);
      }
    }
  float s = wave_reduce(fe_sum);
  if (lane == 0) atomicAdd(fe_acc, (double)s);
}

// ---------------- plain GEMM + f32-vector bias (Arnn pre-activation) ------------
__global__ __launch_bounds__(256)
void gemm_bias(const ushort_t* __restrict__ A, const ushort_t* __restrict__ BT,
               const float* __restrict__ biasv, float* __restrict__ Cf,
               int M, int N, int K) {
  __shared__ ushort_t As[128 * 64];
  __shared__ ushort_t Bs[128 * 64];
  const int tid = threadIdx.x;
  const int lane = tid & 63, wave = tid >> 6;
  const int wm = wave >> 1, wn = wave & 1;
  const int q = lane >> 4, l16 = lane & 15;
  int bx, by;
  xcd_swz(&bx, &by);
  const int m0 = by * 128, n0 = bx * 128;
  (void)lane;

  f32x4 acc[4][4];
#pragma unroll
  for (int i = 0; i < 4; i++)
#pragma unroll
    for (int j = 0; j < 4; j++) acc[i][j] = (f32x4){0.f, 0.f, 0.f, 0.f};

  for (int kk = 0; kk < K; kk += 64) {
#pragma unroll
    for (int j = 0; j < 4; j++) {
      int c = j * 256 + tid;
      int r = c >> 3, bg = (c & 7) ^ (r & 7);
      const int ldso = (j * 256 + wave * 64) * 8;
      GLOAD_LDS16(&A[(size_t)(m0 + r) * K + kk + bg * 8], &As[ldso]);
      GLOAD_LDS16(&BT[(size_t)(n0 + r) * K + kk + bg * 8], &Bs[ldso]);
    }
    __syncthreads();
#pragma unroll
    for (int c = 0; c < 2; c++) {
      bf16x8 af[4], bf[4];
#pragma unroll
      for (int mt = 0; mt < 4; mt++) {
        int r = wm * 64 + mt * 16 + l16;
        af[mt] = *(const bf16x8*)&As[r * 64 + (((c * 4 + q) ^ (r & 7)) * 8)];
      }
#pragma unroll
      for (int nt = 0; nt < 4; nt++) {
        int r = wn * 64 + nt * 16 + l16;
        bf[nt] = *(const bf16x8*)&Bs[r * 64 + (((c * 4 + q) ^ (r & 7)) * 8)];
      }
#pragma unroll
      for (int mt = 0; mt < 4; mt++)
#pragma unroll
        for (int nt = 0; nt < 4; nt++)
          acc[mt][nt] = __builtin_amdgcn_mfma_f32_16x16x32_bf16(
              af[mt], bf[nt], acc[mt][nt], 0, 0, 0);
    }
    __syncthreads();
  }

#pragma unroll
  for (int mt = 0; mt < 4; mt++)
#pragma unroll
    for (int nt = 0; nt < 4; nt++) {
      const int gn = n0 + wn * 64 + nt * 16 + l16;
      const int gmb = m0 + wm * 64 + mt * 16 + q * 4;
      const float bvv = biasv[gn];
#pragma unroll
      for (int rg = 0; rg < 4; rg++)
        Cf[(size_t)(gmb + rg) * N + gn] = acc[mt][nt][rg] + bvv;
    }
}

// ---------------- chunked RNN scan v5 (R10-proven) ----------------
__global__ __launch_bounds__(1024, 1)
void rnn_scan(const float* __restrict__ Apre, const float* __restrict__ Wuu,
              ushort_t* __restrict__ shifted) {
  const int tid = threadIdx.x;
  const int j = tid >> 2;
  const int s = tid & 3;
  const int t_begin = blockIdx.x * 128;
  const int t_end = t_begin + 128;
  const int t0 = (t_begin >= 16) ? (t_begin - 16) : 0;

  float w[64];
#pragma unroll
  for (int i = 0; i < 64; i++) w[i] = Wuu[(size_t)(s * 64 + i) * 256 + j];

  __shared__ float u[2][280];
  __shared__ float asg[32 * 256];
  if (tid < 256) u[0][(tid >> 6) * 68 + (tid & 63)] = 0.f;
  if (blockIdx.x == 0 && s == 0) shifted[j] = 0;
  __syncthreads();

  const int jp = (j >> 6) * 68 + (j & 63);
  int p = 0;
  for (int tb = t0; tb < t_end; tb += 32) {
    int srow = tb + (tid >> 5);
    if (srow >= S_LEN) srow = S_LEN - 1;
    int scol = (tid & 31) * 8;
    float4 a0 = *(const float4*)&Apre[(size_t)srow * 256 + scol];
    float4 a1 = *(const float4*)&Apre[(size_t)srow * 256 + scol + 4];
    *(float4*)&asg[(tid >> 5) * 256 + scol] = a0;
    *(float4*)&asg[(tid >> 5) * 256 + scol + 4] = a1;
    __syncthreads();
#pragma unroll 1
    for (int i = 0; i < 32; i++) {
      const int t = tb + i;
      if (t >= t_end) break;
      float p0 = 0.f, p1 = 0.f, p2 = 0.f, p3 = 0.f;
#pragma unroll
      for (int qq = 0; qq < 64; qq += 4) {
        float4 uv = *(const float4*)&u[p][s * 68 + qq];
        p0 = fmaf(uv.x, w[qq + 0], p0);
        p1 = fmaf(uv.y, w[qq + 1], p1);
        p2 = fmaf(uv.z, w[qq + 2], p2);
        p3 = fmaf(uv.w, w[qq + 3], p3);
      }
      float ps = (p0 + p1) + (p2 + p3);
      ps += __shfl_xor(ps, 1, 64);
      ps += __shfl_xor(ps, 2, 64);
      float z = asg[i * 256 + j] + ps;
      float e = __expf(2.f * z);
      float unew = 1.f - 2.f * __builtin_amdgcn_rcpf(e + 1.f);
      if (s == 0) {
        u[1 - p][jp] = unew;
        if (t >= t_begin && (t + 1) < S_LEN)
          shifted[(size_t)(t + 1) * 256 + j] = f2b(unew);
      }
      __syncthreads();
      p ^= 1;
    }
  }
}

// ---------------- single prep kernel ----------------
__global__ __launch_bounds__(256)
void prep_all(const float* __restrict__ v_seq, ushort_t* __restrict__ vseq_bf,
              const float* __restrict__ Wyv, const float* __restrict__ Wyh1,
              const float* __restrict__ Wyh2, ushort_t* __restrict__ Wycat,
              const float* __restrict__ W1, ushort_t* __restrict__ BTw1t,
              ushort_t* __restrict__ BTw1,
              const float* __restrict__ W2, ushort_t* __restrict__ BTw2t,
              ushort_t* __restrict__ BTw2,
              const float* __restrict__ Wvu, ushort_t* __restrict__ BTwvu,
              const float* __restrict__ bv, const float* __restrict__ bh1,
              const float* __restrict__ bh2, float* __restrict__ bveccat) {
  int b = blockIdx.x;
  const int tid = threadIdx.x;
  if (b < 32768) { int i = b * 256 + tid; vseq_bf[i] = f2b(v_seq[i]); return; }
  b -= 32768;
  if (b < 256)  { int i = b * 256 + tid; Wycat[i] = f2b(Wyv[i]); return; }
  b -= 256;
  if (b < 512)  { int i = b * 256 + tid; Wycat[65536 + i] = f2b(Wyh1[i]); return; }
  b -= 512;
  if (b < 512)  { int i = b * 256 + tid; Wycat[196608 + i] = f2b(Wyh2[i]); return; }
  b -= 512;
  if (b < 512)  { int i = b * 256 + tid; BTw1t[i] = f2b(W1[i]); return; }
  b -= 512;
  if (b < 1024) { int i = b * 256 + tid; BTw2t[i] = f2b(W2[i]); return; }
  b -= 1024;
  if (b < 256)  { int i = b * 256 + tid; int r = i >> 8, c = i & 255;
                  BTwvu[c * 256 + r] = f2b(Wvu[i]); return; }
  b -= 256;
  if (b < 512)  { int i = b * 256 + tid; int r = i >> 9, c = i & 511;
                  BTw1[(size_t)c * 256 + r] = f2b(W1[i]); return; }
  b -= 512;
  if (b < 1024) { int i = b * 256 + tid; int r = i >> 9, c = i & 511;
                  BTw2[(size_t)c * 512 + r] = f2b(W2[i]); return; }
  b -= 1024;
  { int i = b * 256 + tid;
    if (i < 1280)
      bveccat[i] = (i < 256) ? bv[i] : (i < 768) ? bh1[i - 256] : bh2[i - 768]; }
}

__global__ void finalize_kernel(const double* __restrict__ acc, float* __restrict__ out) {
  out[0] = (float)(acc[0] / (double)S_LEN);
  out[1] = (float)(acc[1] / (double)S_LEN);
}

// ---------------- host orchestration ----------------
extern "C" void kernel_launch(void* const* d_in, const int* in_sizes, int n_in,
                              void* d_out, int out_size, void* d_ws, size_t ws_size,
                              hipStream_t stream) {
  (void)in_sizes; (void)n_in; (void)out_size; (void)ws_size;
  const float* v_seq = (const float*)d_in[0];
  const float* W1    = (const float*)d_in[1];
  const float* bv    = (const float*)d_in[2];
  const float* bh1   = (const float*)d_in[3];
  const float* W2    = (const float*)d_in[4];
  const float* bh2   = (const float*)d_in[5];
  const float* Wyv   = (const float*)d_in[6];
  const float* Wyh1  = (const float*)d_in[7];
  const float* Wyh2  = (const float*)d_in[8];
  const float* Wvu   = (const float*)d_in[9];
  const float* Wuu   = (const float*)d_in[10];
  const float* bu    = (const float*)d_in[11];
  float* out = (float*)d_out;

  const size_t SN = (size_t)S_LEN * NV;   // 8.4M
  const size_t SH = (size_t)S_LEN * NH;   // 16.8M
  char* base = (char*)d_ws;
  size_t cur = 0;
  auto take = [&](size_t bytes) { size_t o = cur; cur += (bytes + 255) & ~(size_t)255; return o; };
  double*   acc      = (double*)  (base + take(64));
  ushort_t* BTwvu    = (ushort_t*)(base + take(65536 * 2));
  ushort_t* Wycat    = (ushort_t*)(base + take((size_t)1280 * NR * 2));
  float*    bveccat  = (float*)   (base + take(1280 * 4));
  ushort_t* BTw1     = (ushort_t*)(base + take(131072 * 2));   // W1^T [512,256]
  ushort_t* BTw1t    = (ushort_t*)(base + take(131072 * 2));   // W1   [256,512]
  ushort_t* BTw2     = (ushort_t*)(base + take(262144 * 2));   // W2^T [512,512]
  ushort_t* BTw2t    = (ushort_t*)(base + take(262144 * 2));   // W2   [512,512]
  ushort_t* vseq_bf  = (ushort_t*)(base + take(SN * 2));
  ushort_t* shifted  = (ushort_t*)(base + take(SN * 2));
  float*    Arnn     = (float*)   (base + take(SN * 4));       // RNN pre-activation
  ushort_t* h1buf    = (ushort_t*)(base + take(SH * 2));       // h1 probs (kept!)
  ushort_t* sampA    = (ushort_t*)(base + take(SH * 2));       // RBM1 h samples
  ushort_t* sampB    = (ushort_t*)(base + take(SN * 2));       // RBM1 v samples
  ushort_t* sampC    = (ushort_t*)(base + take(SH * 2));       // RBM2 h2 samples
  ushort_t* sampD    = (ushort_t*)(base + take(SH * 2));       // RBM2 h1 samples

  uint32_t ka[20], kb[20];
  uint32_t K0 = 0u, K1 = 42u;
  for (int it = 0; it < 10; it++) {
    uint32_t n0, n1, a0, a1, b0, b1;
    tf2x32(K0, K1, 0u, 0u, &n0, &n1);
    tf2x32(K0, K1, 0u, 1u, &a0, &a1);
    tf2x32(K0, K1, 0u, 2u, &b0, &b1);
    ka[2 * it] = a0; kb[2 * it] = a1;
    ka[2 * it + 1] = b0; kb[2 * it + 1] = b1;
    K0 = n0; K1 = n1;
  }

  hipMemsetAsync(acc, 0, 2 * sizeof(double), stream);

  dim3 blk(256);
  prep_all<<<dim3(37381), blk, 0, stream>>>(
      v_seq, vseq_bf, Wyv, Wyh1, Wyh2, Wycat, W1, BTw1t, BTw1,
      W2, BTw2t, BTw2, Wvu, BTwvu, bv, bh1, bh2, bveccat);

  const int M = S_LEN;
  gemm_bias<<<dim3(2, M / 128), blk, 0, stream>>>(
      vseq_bf, BTwvu, bu, Arnn, M, NV, NV);
  rnn_scan<<<dim3(S_LEN / 128), dim3(1024), 0, stream>>>(Arnn, Wuu, shifted);

  const int OFF_BV = 0, OFF_BH1 = NV, OFF_BH2 = NV + NH;
  auto mk = [&](const ushort_t* A, const ushort_t* BT, int boff, ushort_t* C,
                ushort_t* C2, const float* vs, float sign, int key, int N, int K) {
    GemmArgs g;
    g.A = A; g.BT = BT;
    g.Ax = shifted;
    g.BXT = Wycat + (size_t)boff * 256;
    g.bvec = bveccat + boff;
    g.C = C; g.C2 = C2; g.vseqf = vs;
    g.fe_acc = acc; g.mon_acc = acc + 1; g.sign = sign;
    g.rk0 = key >= 0 ? ka[key] : 0; g.rk1 = key >= 0 ? kb[key] : 0;
    g.N = N; g.K = K; g.nbx = N / 128;
    return g;
  };

  // G1: sample h (sampA), h1 probs (h1buf), cost1 -= softplus(v_seq@W1+bh1t)
  gemm_samp<F_SAMP | F_H1 | F_FE>
      <<<dim3(4, M / 128), blk, 0, stream>>>(
      mk(vseq_bf, BTw1, OFF_BH1, sampA, h1buf, nullptr, 1.0f, 0, NH, NV));

  // 10 flattened pair dispatches: RBM1 chain + RBM2 chain
  GemmArgs V[5], Hh[4], A2g[5], B2g[5];
  for (int it = 0; it < 5; it++) {
    if (it > 0)
      Hh[it - 1] = mk(sampB, BTw1, OFF_BH1, sampA, nullptr, nullptr, 0.f,
                      2 * it, NH, NV);
    V[it] = mk(sampA, BTw1t, OFF_BV, sampB, nullptr,
               (it == 4) ? v_seq : nullptr, 0.f, 2 * it + 1, NV, NH);
    A2g[it] = mk((it == 0) ? h1buf : sampD,
                 BTw2, OFF_BH2, sampC, nullptr, nullptr,
                 (it == 0) ? 1.0f : 0.f, 10 + 2 * it, NH, NH);
    B2g[it] = mk(sampC, BTw2t, OFF_BH1, sampD, nullptr, nullptr, 0.f,
                 11 + 2 * it, NH, NH);
  }
  GemmArgs FE1 = mk(sampB, BTw1, OFF_BH1, nullptr, nullptr, nullptr, -1.0f,
                    -1, NH, NV);
  GemmArgs FE2 = mk(sampD, BTw2, OFF_BH2, nullptr, nullptr, nullptr, -1.0f,
                    -1, NH, NH);

  auto pgrid = [&](const GemmArgs& a, const GemmArgs& b) {
    return dim3(a.nbx + b.nbx, M / 128);
  };

  gemm_pair<F_SAMP, F_SAMP | F_FE>
      <<<pgrid(V[0], A2g[0]), blk, 0, stream>>>(V[0], A2g[0]);  // A2g[0]: A=h1buf
  gemm_pair<F_SAMP, F_SAMP>
      <<<pgrid(Hh[0], B2g[0]), blk, 0, stream>>>(Hh[0], B2g[0]);
  gemm_pair<F_SAMP, F_SAMP>
      <<<pgrid(V[1], A2g[1]), blk, 0, stream>>>(V[1], A2g[1]);
  gemm_pair<F_SAMP, F_SAMP>
      <<<pgrid(Hh[1], B2g[1]), blk, 0, stream>>>(Hh[1], B2g[1]);
  gemm_pair<F_SAMP, F_SAMP>
      <<<pgrid(V[2], A2g[2]), blk, 0, stream>>>(V[2], A2g[2]);
  gemm_pair<F_SAMP, F_SAMP>
      <<<pgrid(Hh[2], B2g[2]), blk, 0, stream>>>(Hh[2], B2g[2]);
  gemm_pair<F_SAMP, F_SAMP>
      <<<pgrid(V[3], A2g[3]), blk, 0, stream>>>(V[3], A2g[3]);
  gemm_pair<F_SAMP, F_SAMP>
      <<<pgrid(Hh[3], B2g[3]), blk, 0, stream>>>(Hh[3], B2g[3]);
  gemm_pair<F_SAMP | F_MON, F_SAMP>
      <<<pgrid(V[4], A2g[4]), blk, 0, stream>>>(V[4], A2g[4]);
  gemm_pair<F_FE, F_SAMP>
      <<<pgrid(FE1, B2g[4]), blk, 0, stream>>>(FE1, B2g[4]);

  // FE2(sample): cost2 += softplus(h1s@W2 + bh2t)
  gemm_samp<F_FE><<<dim3(4, M / 128), blk, 0, stream>>>(FE2);

  // Bias-dot terms (moved out of the hot GEMMs):
  // cost1 += sum (v_samp_final - v_seq) . bv_t      [X1=sampB, X2=v_seq f32]
  dot_bias<true><<<dim3(2, M / 128), blk, 0, stream>>>(
      shifted, Wycat + (size_t)OFF_BV * 256, bveccat + OFF_BV,
      sampB, v_seq, acc, NV);
  // cost2 += sum (h1_samp_final - h1) . bh1t        [X1=sampD, X2=h1buf bf16]
  dot_bias<false><<<dim3(4, M / 128), blk, 0, stream>>>(
      shifted, Wycat + (size_t)OFF_BH1 * 256, bveccat + OFF_BH1,
      sampD, h1buf, acc, NH);

  finalize_kernel<<<1, 1, 0, stream>>>(acc, out);
}